// Round 3
// baseline (3923.691 us; speedup 1.0000x reference)
//
#include <hip/hip_runtime.h>
#include <hip/hip_bf16.h>
#include <math.h>

#define TLEN 2048
#define HDIM 1024
#define NHEAD 16
#define HEADD 64
#define NKVH 4
#define SINKN 128
#define WINN 256
#define STATEN 256
#define KCONV 4
#define MINTN 1024
#define CONVD 3072
#define DPROJ 4112
#define INTERN 4096
#define LMN 1664
#define TCN 385
#define EPSF 1e-6f

__device__ __forceinline__ float siluf(float x){ return x / (1.0f + expf(-x)); }
__device__ __forceinline__ float softplusf_(float x){ return fmaxf(x, 0.0f) + log1pf(expf(-fabsf(x))); }

__device__ __forceinline__ float block_sum256(float v, float* sb){
#pragma unroll
  for (int m = 32; m > 0; m >>= 1) v += __shfl_xor(v, m);
  int wid = threadIdx.x >> 6;
  if ((threadIdx.x & 63) == 0) sb[wid] = v;
  __syncthreads();
  return sb[0] + sb[1] + sb[2] + sb[3];
}

// ---------------- rmsnorm (row = 1024 floats, 256 thr x float4) ----------------
__global__ __launch_bounds__(256) void rmsnorm_k(const float* __restrict__ in, const float* __restrict__ w,
                                                 float* __restrict__ out){
  __shared__ float sb[4];
  size_t r = blockIdx.x;
  float4 x = ((const float4*)(in + r*HDIM))[threadIdx.x];
  float ss = block_sum256(x.x*x.x + x.y*x.y + x.z*x.z + x.w*x.w, sb);
  float sc = 1.0f / sqrtf(ss*(1.0f/HDIM) + EPSF);
  float4 wv = ((const float4*)w)[threadIdx.x];
  ((float4*)(out + r*HDIM))[threadIdx.x] =
      make_float4(x.x*sc*wv.x, x.y*sc*wv.y, x.z*sc*wv.z, x.w*sc*wv.w);
}

// y = ys * silu(z);  out = rmsnorm(y) * w      (z = proj[:, 0:1024])
__global__ __launch_bounds__(256) void gated_rmsnorm_k(const float* __restrict__ ys, const float* __restrict__ proj,
                                                       const float* __restrict__ w, float* __restrict__ out){
  __shared__ float sb[4];
  size_t r = blockIdx.x;
  float4 y = ((const float4*)(ys + r*MINTN))[threadIdx.x];
  float4 z = ((const float4*)(proj + r*DPROJ))[threadIdx.x];
  y.x *= siluf(z.x); y.y *= siluf(z.y); y.z *= siluf(z.z); y.w *= siluf(z.w);
  float ss = block_sum256(y.x*y.x + y.y*y.y + y.z*y.z + y.w*y.w, sb);
  float sc = 1.0f / sqrtf(ss*(1.0f/MINTN) + EPSF);
  float4 wv = ((const float4*)w)[threadIdx.x];
  ((float4*)(out + r*MINTN))[threadIdx.x] =
      make_float4(y.x*sc*wv.x, y.y*sc*wv.y, y.z*sc*wv.z, y.w*sc*wv.w);
}

// ---------------- fp32 tiled GEMM: C[M,N] = A[M,K] @ B[K,N] (+epilogue) ----------------
// BM=128 BN=64 BK=16, 256 threads, 8x4 micro-tile.
// EPI: 0 none, 1 +=bias[n], 2 +=extra[m,n]
template<int EPI>
__global__ __launch_bounds__(256) void gemm_k(const float* __restrict__ A, const float* __restrict__ B,
                                              float* __restrict__ C, const float* __restrict__ bias,
                                              const float* __restrict__ extra, int M, int N, int K){
  __shared__ float As[16][132];  // transposed A tile, padded (2-way bank alias max)
  __shared__ float Bs[16][64];
  int tid = threadIdx.x;
  int tx = tid & 15, ty = tid >> 4;
  int m0 = blockIdx.y * 128, n0 = blockIdx.x * 64;
  int ar = tid >> 2, ak = (tid & 3) * 4;   // A: rows ar, ar+64; k-cols ak..ak+3
  int bk = tid >> 4, bn = (tid & 15) * 4;  // B: row bk, cols bn..bn+3
  float acc[8][4];
#pragma unroll
  for (int i = 0; i < 8; i++)
#pragma unroll
    for (int j = 0; j < 4; j++) acc[i][j] = 0.f;

  for (int k0 = 0; k0 < K; k0 += 16){
    float4 a0 = make_float4(0,0,0,0), a1 = make_float4(0,0,0,0), b0 = make_float4(0,0,0,0);
    if (m0 + ar < M)      a0 = *(const float4*)(A + (size_t)(m0+ar)*K + k0 + ak);
    if (m0 + ar + 64 < M) a1 = *(const float4*)(A + (size_t)(m0+ar+64)*K + k0 + ak);
    if (n0 + bn < N)      b0 = *(const float4*)(B + (size_t)(k0+bk)*N + n0 + bn);
    __syncthreads();
    As[ak+0][ar] = a0.x; As[ak+1][ar] = a0.y; As[ak+2][ar] = a0.z; As[ak+3][ar] = a0.w;
    As[ak+0][ar+64] = a1.x; As[ak+1][ar+64] = a1.y; As[ak+2][ar+64] = a1.z; As[ak+3][ar+64] = a1.w;
    *(float4*)&Bs[bk][bn] = b0;
    __syncthreads();
#pragma unroll
    for (int kk = 0; kk < 16; kk++){
      float a[8], b[4];
      *(float4*)(a)   = *(const float4*)&As[kk][ty*8];
      *(float4*)(a+4) = *(const float4*)&As[kk][ty*8+4];
      *(float4*)(b)   = *(const float4*)&Bs[kk][tx*4];
#pragma unroll
      for (int i = 0; i < 8; i++)
#pragma unroll
        for (int j = 0; j < 4; j++) acc[i][j] = fmaf(a[i], b[j], acc[i][j]);
    }
  }
  int n = n0 + tx*4;
  if (n >= N) return;   // N is always a multiple of 4; whole float4 valid or not
#pragma unroll
  for (int i = 0; i < 8; i++){
    int m = m0 + ty*8 + i;
    if (m >= M) break;
    float r0 = acc[i][0], r1 = acc[i][1], r2 = acc[i][2], r3 = acc[i][3];
    if (EPI == 1){ r0 += bias[n]; r1 += bias[n+1]; r2 += bias[n+2]; r3 += bias[n+3]; }
    if (EPI == 2){ const float* e = extra + (size_t)m*N + n; r0 += e[0]; r1 += e[1]; r2 += e[2]; r3 += e[3]; }
    *(float4*)(C + (size_t)m*N + n) = make_float4(r0, r1, r2, r3);
  }
}

// ---------------- fused gate/up GEMM: C = silu(A@G) * (A@U) ----------------
// Same tile geometry as gemm_k; two B-operands staged, two accumulators.
__global__ __launch_bounds__(256) void gemm_gateup_k(const float* __restrict__ A, const float* __restrict__ G,
                                                     const float* __restrict__ U, float* __restrict__ C,
                                                     int M, int N, int K){
  __shared__ float As[16][132];
  __shared__ float Gs[16][64];
  __shared__ float Us[16][64];
  int tid = threadIdx.x;
  int tx = tid & 15, ty = tid >> 4;
  int m0 = blockIdx.y * 128, n0 = blockIdx.x * 64;
  int ar = tid >> 2, ak = (tid & 3) * 4;
  int bk = tid >> 4, bn = (tid & 15) * 4;
  float accg[8][4], accu[8][4];
#pragma unroll
  for (int i = 0; i < 8; i++)
#pragma unroll
    for (int j = 0; j < 4; j++){ accg[i][j] = 0.f; accu[i][j] = 0.f; }

  for (int k0 = 0; k0 < K; k0 += 16){
    float4 a0 = *(const float4*)(A + (size_t)(m0+ar)*K + k0 + ak);
    float4 a1 = *(const float4*)(A + (size_t)(m0+ar+64)*K + k0 + ak);
    float4 g0 = *(const float4*)(G + (size_t)(k0+bk)*N + n0 + bn);
    float4 u0 = *(const float4*)(U + (size_t)(k0+bk)*N + n0 + bn);
    __syncthreads();
    As[ak+0][ar] = a0.x; As[ak+1][ar] = a0.y; As[ak+2][ar] = a0.z; As[ak+3][ar] = a0.w;
    As[ak+0][ar+64] = a1.x; As[ak+1][ar+64] = a1.y; As[ak+2][ar+64] = a1.z; As[ak+3][ar+64] = a1.w;
    *(float4*)&Gs[bk][bn] = g0;
    *(float4*)&Us[bk][bn] = u0;
    __syncthreads();
#pragma unroll
    for (int kk = 0; kk < 16; kk++){
      float a[8], g[4], u[4];
      *(float4*)(a)   = *(const float4*)&As[kk][ty*8];
      *(float4*)(a+4) = *(const float4*)&As[kk][ty*8+4];
      *(float4*)(g)   = *(const float4*)&Gs[kk][tx*4];
      *(float4*)(u)   = *(const float4*)&Us[kk][tx*4];
#pragma unroll
      for (int i = 0; i < 8; i++)
#pragma unroll
        for (int j = 0; j < 4; j++){
          accg[i][j] = fmaf(a[i], g[j], accg[i][j]);
          accu[i][j] = fmaf(a[i], u[j], accu[i][j]);
        }
    }
  }
  int n = n0 + tx*4;
#pragma unroll
  for (int i = 0; i < 8; i++){
    int m = m0 + ty*8 + i;
    *(float4*)(C + (size_t)m*N + n) =
        make_float4(siluf(accg[i][0])*accu[i][0], siluf(accg[i][1])*accu[i][1],
                    siluf(accg[i][2])*accu[i][2], siluf(accg[i][3])*accu[i][3]);
  }
}

// ---------------- causal depthwise conv (K=4) + silu over xBC cols ----------------
__global__ __launch_bounds__(256) void conv_silu_k(const float* __restrict__ proj, const float* __restrict__ cw,
                                                   const float* __restrict__ cb, float* __restrict__ out){
  int idx = blockIdx.x*256 + threadIdx.x;
  if (idx >= LMN*CONVD) return;
  int c = idx % CONVD;
  int t = idx / CONVD;
  float acc = cb[c];
#pragma unroll
  for (int kk = 0; kk < KCONV; kk++){
    int ts = t + kk - (KCONV-1);
    if (ts >= 0) acc = fmaf(proj[(size_t)ts*DPROJ + MINTN + c], cw[c*KCONV + kk], acc);
  }
  out[idx] = siluf(acc);
}

__global__ __launch_bounds__(256) void dtprep_k(const float* __restrict__ proj, const float* __restrict__ dtb,
                                                const float* __restrict__ alog, float* __restrict__ dt,
                                                float* __restrict__ dA){
  int idx = blockIdx.x*256 + threadIdx.x;
  if (idx >= LMN*NHEAD) return;
  int h = idx & 15, t = idx >> 4;
  float d = softplusf_(proj[(size_t)t*DPROJ + MINTN + CONVD + h] + dtb[h]);
  dt[idx] = d;
  dA[idx] = expf(-d * expf(alog[h]));
}

// ---------------- sequential SSM scan, depth-4 register prefetch ----------------
// 64 blocks = 16 heads x 4 d-groups(16 d each). 256 thr: d = dg*16 + tid/16, n-chunk = tid%16.
// Serial 1664-step chain is L3-latency-bound at prefetch distance 1 (~460cy/iter);
// four named slots (no runtime indexing -> no scratch) give ~3.7-iter prefetch distance.
#define SLOAD(Bs, Cs, xs, dts, dAs, tt) do {                                   \
    size_t o_ = (size_t)(tt)*CONVD;                                            \
    xs = xp[o_]; dts = dtb[(tt)*NHEAD + h]; dAs = dAb[(tt)*NHEAD + h];         \
    Bs[0] = ((const float4*)(Bp + o_))[0]; Bs[1] = ((const float4*)(Bp + o_))[1]; \
    Bs[2] = ((const float4*)(Bp + o_))[2]; Bs[3] = ((const float4*)(Bp + o_))[3]; \
    Cs[0] = ((const float4*)(Cp + o_))[0]; Cs[1] = ((const float4*)(Cp + o_))[1]; \
    Cs[2] = ((const float4*)(Cp + o_))[2]; Cs[3] = ((const float4*)(Cp + o_))[3]; \
  } while(0)

#define SSTEP(Bs, Cs, xs, dts, dAs, tt) do {                                   \
    float coef_ = dts * xs;                                                    \
    float accp_[4] = {0.f,0.f,0.f,0.f};                                        \
    const float* bf_ = (const float*)Bs; const float* cf_ = (const float*)Cs;  \
    _Pragma("unroll")                                                          \
    for (int i_ = 0; i_ < 16; i_++){                                           \
      s[i_] = fmaf(s[i_], dAs, coef_*bf_[i_]);                                 \
      accp_[i_ & 3] = fmaf(s[i_], cf_[i_], accp_[i_ & 3]);                     \
    }                                                                          \
    float accv_ = (accp_[0]+accp_[1])+(accp_[2]+accp_[3]);                     \
    accv_ += __shfl_xor(accv_, 1); accv_ += __shfl_xor(accv_, 2);              \
    accv_ += __shfl_xor(accv_, 4); accv_ += __shfl_xor(accv_, 8);              \
    if (nc == 0) ys[(size_t)(tt)*MINTN + h*HEADD + d] = accv_ + Dh*xs;         \
  } while(0)

__global__ __launch_bounds__(256, 1) void scan_k(const float* __restrict__ cv, const float* __restrict__ dtb,
                                                 const float* __restrict__ dAb, const float* __restrict__ Dp,
                                                 float* __restrict__ ys){
  int h = blockIdx.x >> 2;
  int d = (blockIdx.x & 3)*16 + (threadIdx.x >> 4);
  int nc = threadIdx.x & 15;
  int g = h >> 2;
  const float* xp = cv + h*HEADD + d;
  const float* Bp = cv + MINTN + g*STATEN + nc*16;
  const float* Cp = cv + MINTN + 1024 + g*STATEN + nc*16;
  float Dh = Dp[h];
  float s[16];
#pragma unroll
  for (int i = 0; i < 16; i++) s[i] = 0.f;

  float4 B0[4], C0[4], B1[4], C1[4], B2[4], C2[4], B3[4], C3[4];
  float x0, dt0, dA0, x1, dt1, dA1, x2, dt2, dA2, x3, dt3, dA3;
  SLOAD(B0, C0, x0, dt0, dA0, 0);
  SLOAD(B1, C1, x1, dt1, dA1, 1);
  SLOAD(B2, C2, x2, dt2, dA2, 2);
  SLOAD(B3, C3, x3, dt3, dA3, 3);

  for (int t = 0; t < LMN; t += 4){
    SSTEP(B0, C0, x0, dt0, dA0, t+0);
    { int tn = (t+4 > LMN-1) ? LMN-1 : t+4; SLOAD(B0, C0, x0, dt0, dA0, tn); }
    SSTEP(B1, C1, x1, dt1, dA1, t+1);
    { int tn = (t+5 > LMN-1) ? LMN-1 : t+5; SLOAD(B1, C1, x1, dt1, dA1, tn); }
    SSTEP(B2, C2, x2, dt2, dA2, t+2);
    { int tn = (t+6 > LMN-1) ? LMN-1 : t+6; SLOAD(B2, C2, x2, dt2, dA2, tn); }
    SSTEP(B3, C3, x3, dt3, dA3, t+3);
    { int tn = (t+7 > LMN-1) ? LMN-1 : t+7; SLOAD(B3, C3, x3, dt3, dA3, tn); }
  }
}

// ---------------- small assembly kernels ----------------
__global__ __launch_bounds__(256) void build_hc_k(const float* __restrict__ hn, const float* __restrict__ memo,
                                                  float* __restrict__ hc){
  int idx = blockIdx.x*256 + threadIdx.x;
  if (idx >= TCN*HDIM) return;
  int r = idx >> 10, c = idx & 1023;
  float v;
  if (r < SINKN)        v = hn[(size_t)r*HDIM + c];
  else if (r == SINKN)  v = memo[(size_t)(LMN-1)*HDIM + c];
  else                  v = hn[(size_t)(r + 1663)*HDIM + c];
  hc[idx] = v;
}

__global__ __launch_bounds__(256) void rope_k(float* __restrict__ q, float* __restrict__ k,
                                              const float* __restrict__ cosp, const float* __restrict__ sinp){
  int idx = blockIdx.x*256 + threadIdx.x;
  if (idx >= TCN*20*32) return;
  int dd = idx & 31;
  int hh = (idx >> 5) % 20;
  int t  = idx / (20*32);
  int ci = (t <= SINKN) ? t : t + 1663;
  float* p = (hh < NHEAD) ? (q + (size_t)t*HDIM + hh*HEADD)
                          : (k + (size_t)t*(NKVH*HEADD) + (hh - NHEAD)*HEADD);
  float a = p[dd], b = p[dd+32];
  float c0 = cosp[(size_t)ci*HEADD + dd], c1 = cosp[(size_t)ci*HEADD + dd + 32];
  float s0 = sinp[(size_t)ci*HEADD + dd], s1 = sinp[(size_t)ci*HEADD + dd + 32];
  p[dd]    = a*c0 - b*s0;
  p[dd+32] = b*c1 + a*s1;
}

// ---------------- flash-style fp32 attention, Tc=385, causal, GQA 16q/4kv ----------------
__global__ __launch_bounds__(256) void attn_k(const float* __restrict__ q, const float* __restrict__ k,
                                              const float* __restrict__ v, float* __restrict__ aoc){
  __shared__ float Qs[64][65];   // Q tile; reused as P tile after hoist
  __shared__ float Ks[64][65];
  __shared__ float Vs[64][68];
  int qt = blockIdx.x, h = blockIdx.y;
  int tid = threadIdx.x;
  int ql = tid >> 2, dg = tid & 3;
  int qg = qt*64 + ql;
  int kvh = h >> 2;
#pragma unroll
  for (int i = 0; i < 16; i++){
    int idx = tid + 256*i;
    int r = idx >> 6, c = idx & 63;
    int qr = qt*64 + r;
    Qs[r][c] = (qr < TCN) ? q[(size_t)qr*HDIM + h*HEADD + c] : 0.f;
  }
  __syncthreads();
  float qreg[64];
#pragma unroll
  for (int d2 = 0; d2 < 64; d2++) qreg[d2] = Qs[ql][d2];
  __syncthreads();  // Qs is reused as P storage below

  float mrun = -INFINITY, lrun = 0.f;
  float acc[16];
#pragma unroll
  for (int i = 0; i < 16; i++) acc[i] = 0.f;

  for (int kt = 0; kt <= qt; kt++){
    __syncthreads();
#pragma unroll
    for (int i = 0; i < 16; i++){
      int idx = tid + 256*i;
      int r = idx >> 6, c = idx & 63;
      int kr = kt*64 + r;
      float kv = 0.f, vv = 0.f;
      if (kr < TCN){
        kv = k[(size_t)kr*(NKVH*HEADD) + kvh*HEADD + c];
        vv = v[(size_t)kr*(NKVH*HEADD) + kvh*HEADD + c];
      }
      Ks[r][c] = kv; Vs[r][c] = vv;
    }
    __syncthreads();
    float p[16]; float tmax = -INFINITY;
#pragma unroll
    for (int jj = 0; jj < 16; jj++){
      int j = jj*4 + dg;            // key-interleave keeps LDS banks conflict-free
      float sv = 0.f;
#pragma unroll
      for (int d2 = 0; d2 < 64; d2++) sv = fmaf(qreg[d2], Ks[j][d2], sv);
      sv *= 0.125f;                  // HD^-0.5
      int kr = kt*64 + j;
      if (kr > qg || kr >= TCN) sv = -INFINITY;
      p[jj] = sv;
      tmax = fmaxf(tmax, sv);
    }
    tmax = fmaxf(tmax, __shfl_xor(tmax, 1));
    tmax = fmaxf(tmax, __shfl_xor(tmax, 2));
    float nm = fmaxf(mrun, tmax);
    if (nm == -INFINITY) nm = 0.f;  // fully-masked rows: avoid NaN
    float sc = expf(mrun - nm);
    float sump = 0.f;
#pragma unroll
    for (int jj = 0; jj < 16; jj++){ p[jj] = expf(p[jj] - nm); sump += p[jj]; }
    sump += __shfl_xor(sump, 1);
    sump += __shfl_xor(sump, 2);
    lrun = lrun*sc + sump;
    mrun = nm;
#pragma unroll
    for (int i = 0; i < 16; i++) acc[i] *= sc;
#pragma unroll
    for (int jj = 0; jj < 16; jj++) Qs[ql][jj*4 + dg] = p[jj];
    __syncthreads();
#pragma unroll
    for (int j = 0; j < 64; j++){
      float pv = Qs[ql][j];
#pragma unroll
      for (int c4 = 0; c4 < 4; c4++){
        float4 vv = *(const float4*)&Vs[j][dg*16 + c4*4];
        acc[c4*4+0] = fmaf(pv, vv.x, acc[c4*4+0]);
        acc[c4*4+1] = fmaf(pv, vv.y, acc[c4*4+1]);
        acc[c4*4+2] = fmaf(pv, vv.z, acc[c4*4+2]);
        acc[c4*4+3] = fmaf(pv, vv.w, acc[c4*4+3]);
      }
    }
  }
  if (qg < TCN){
    float inv = 1.0f / lrun;
#pragma unroll
    for (int c4 = 0; c4 < 4; c4++){
      *(float4*)(aoc + (size_t)qg*HDIM + h*HEADD + dg*16 + c4*4) =
          make_float4(acc[c4*4]*inv, acc[c4*4+1]*inv, acc[c4*4+2]*inv, acc[c4*4+3]*inv);
    }
  }
}

__global__ __launch_bounds__(256) void build_ao_k(const float* __restrict__ aoc, const float* __restrict__ memo,
                                                  float* __restrict__ aof){
  int idx = blockIdx.x*256 + threadIdx.x;
  if (idx >= TLEN*HDIM) return;
  int r = idx >> 10, c = idx & 1023;
  float v;
  if (r < SINKN)              v = aoc[(size_t)r*HDIM + c];
  else if (r < TLEN - WINN)   v = memo[(size_t)(r - SINKN)*HDIM + c];
  else                        v = aoc[(size_t)(r - 1663)*HDIM + c];
  aof[idx] = v;
}

extern "C" void kernel_launch(void* const* d_in, const int* in_sizes, int n_in,
                              void* d_out, int out_size, void* d_ws, size_t ws_size,
                              hipStream_t stream){
  (void)in_sizes; (void)n_in; (void)out_size; (void)ws_size;
  const float* x      = (const float*)d_in[0];
  const float* cosp   = (const float*)d_in[1];
  const float* sinp   = (const float*)d_in[2];
  const float* ln1_w  = (const float*)d_in[3];
  const float* q_w    = (const float*)d_in[4];
  const float* q_b    = (const float*)d_in[5];
  const float* k_w    = (const float*)d_in[6];
  const float* k_b    = (const float*)d_in[7];
  const float* v_w    = (const float*)d_in[8];
  const float* v_b    = (const float*)d_in[9];
  const float* o_w    = (const float*)d_in[10];
  const float* inpw   = (const float*)d_in[11];
  const float* convw  = (const float*)d_in[12];
  const float* convb  = (const float*)d_in[13];
  const float* dtbias = (const float*)d_in[14];
  const float* alog   = (const float*)d_in[15];
  const float* Dp     = (const float*)d_in[16];
  const float* mnw    = (const float*)d_in[17];
  const float* moutw  = (const float*)d_in[18];
  const float* ln2_w  = (const float*)d_in[19];
  const float* gatew  = (const float*)d_in[20];
  const float* upw    = (const float*)d_in[21];
  const float* downw  = (const float*)d_in[22];
  float* out = (float*)d_out;

  // Workspace overlay (floats; step liveness). Peak = 15,808,512 floats = 60.3 MiB.
  //   hn    @0          [0, 2,097,152)        live 1-8 ; h1 reuses @0 (15-19)
  //   proj  @2,097,152  [.., 8,939,520)       live 2-6 ; aof (14-15) / mlpin (16-18) reuse front
  //   conv  @8,939,520  [.., 14,051,328)      live 3-5 ; memo/mamx reuse after
  //   memo  @8,939,520  [.., 10,643,456)      live 7-14
  //   mamx  @10,643,456 [.., 12,347,392)      live 6-7
  //   dtb   @14,051,328 [.., 14,077,952)      live 4-5
  //   dAb   @14,077,952 [.., 14,104,576)      live 4-5
  //   yscan @14,104,576 [.., 15,808,512)      live 5-6 ; hc/qb/kb/vb/aoc reuse after
  //   hc    @14,104,576 [.., 14,498,816)      live 8-11
  //   qb    @14,498,816 [.., 14,893,056)      live 9-13
  //   kb    @14,893,056 [.., 14,991,616)      live 9-13
  //   vb    @14,991,616 [.., 15,090,176)      live 9-13
  //   aoc   @15,090,176 [.., 15,484,416)      live 13-14
  //   gu    @4,194,304  [.., 12,582,912)      live 17-19 (over dead proj-tail/memo/mamx)
  float* w     = (float*)d_ws;
  float* hn    = w + 0;
  float* proj  = w + 2097152;
  float* conv  = w + 8939520;
  float* memo  = w + 8939520;
  float* mamx  = w + 10643456;
  float* dtb   = w + 14051328;
  float* dAb   = w + 14077952;
  float* yscan = w + 14104576;
  float* hc    = w + 14104576;
  float* qb    = w + 14498816;
  float* kb    = w + 14893056;
  float* vb    = w + 14991616;
  float* aoc   = w + 15090176;
  float* aof   = w + 2097152;
  float* h1    = w + 0;
  float* mlpin = w + 2097152;
  float* gu    = w + 4194304;

  // 1. ln1
  rmsnorm_k<<<TLEN, 256, 0, stream>>>(x, ln1_w, hn);
  // 2. mamba in_proj on evicted rows [128,1792)
  gemm_k<0><<<dim3(65, 13), 256, 0, stream>>>(hn + (size_t)SINKN*HDIM, inpw, proj, nullptr, nullptr, LMN, DPROJ, HDIM);
  // 3. conv + silu
  conv_silu_k<<<(LMN*CONVD + 255)/256, 256, 0, stream>>>(proj, convw, convb, conv);
  // 4. dt = softplus(dt+bias), dA = exp(dt*A)
  dtprep_k<<<(LMN*NHEAD + 255)/256, 256, 0, stream>>>(proj, dtbias, alog, dtb, dAb);
  // 5. sequential scan -> y + D*x
  scan_k<<<64, 256, 0, stream>>>(conv, dtb, dAb, Dp, yscan);
  // 6. gate by silu(z), rmsnorm
  gated_rmsnorm_k<<<LMN, 256, 0, stream>>>(yscan, proj, mnw, mamx);
  // 7. mamba out proj
  gemm_k<0><<<dim3(16, 13), 256, 0, stream>>>(mamx, moutw, memo, nullptr, nullptr, LMN, HDIM, HDIM);
  // 8. compressed sequence hc (385 tokens)
  build_hc_k<<<(TCN*HDIM + 255)/256, 256, 0, stream>>>(hn, memo, hc);
  // 9-11. qkv projections (+bias)
  gemm_k<1><<<dim3(16, 4), 256, 0, stream>>>(hc, q_w, qb, q_b, nullptr, TCN, HDIM, HDIM);
  gemm_k<1><<<dim3(4, 4), 256, 0, stream>>>(hc, k_w, kb, k_b, nullptr, TCN, NKVH*HEADD, HDIM);
  gemm_k<1><<<dim3(4, 4), 256, 0, stream>>>(hc, v_w, vb, v_b, nullptr, TCN, NKVH*HEADD, HDIM);
  // 12. rope on q,k (concatenated cos/sin indexing)
  rope_k<<<(TCN*20*32 + 255)/256, 256, 0, stream>>>(qb, kb, cosp, sinp);
  // 13. causal attention
  attn_k<<<dim3(7, 16), 256, 0, stream>>>(qb, kb, vb, aoc);
  // 14. splice mem_out back into full-length ao
  build_ao_k<<<(TLEN*HDIM + 255)/256, 256, 0, stream>>>(aoc, memo, aof);
  // 15. o_proj + residual x -> h1
  gemm_k<2><<<dim3(16, 16), 256, 0, stream>>>(aof, o_w, h1, nullptr, x, TLEN, HDIM, HDIM);
  // 16. ln2
  rmsnorm_k<<<TLEN, 256, 0, stream>>>(h1, ln2_w, mlpin);
  // 17. fused gate/up proj: gu = silu(mlpin@gate_w) * (mlpin@up_w)
  gemm_gateup_k<<<dim3(64, 16), 256, 0, stream>>>(mlpin, gatew, upw, gu, TLEN, INTERN, HDIM);
  // 18. down proj + residual h1 -> out
  gemm_k<2><<<dim3(16, 16), 256, 0, stream>>>(gu, downw, out, nullptr, h1, TLEN, HDIM, INTERN);
}

// Round 5
// 2254.958 us; speedup vs baseline: 1.7400x; 1.7400x over previous
//
#include <hip/hip_runtime.h>
#include <hip/hip_bf16.h>
#include <math.h>

#define TLEN 2048
#define HDIM 1024
#define NHEAD 16
#define HEADD 64
#define NKVH 4
#define SINKN 128
#define WINN 256
#define STATEN 256
#define KCONV 4
#define MINTN 1024
#define CONVD 3072
#define DPROJ 4112
#define INTERN 4096
#define LMN 1664
#define TCN 385
#define EPSF 1e-6f
#define SCHUNK 128
#define NCHUNK 13   /* 13*128 = 1664 */

__device__ __forceinline__ float siluf(float x){ return x / (1.0f + expf(-x)); }
__device__ __forceinline__ float softplusf_(float x){ return fmaxf(x, 0.0f) + log1pf(expf(-fabsf(x))); }

__device__ __forceinline__ float block_sum256(float v, float* sb){
#pragma unroll
  for (int m = 32; m > 0; m >>= 1) v += __shfl_xor(v, m);
  int wid = threadIdx.x >> 6;
  if ((threadIdx.x & 63) == 0) sb[wid] = v;
  __syncthreads();
  return sb[0] + sb[1] + sb[2] + sb[3];
}

// ---------------- rmsnorm (row = 1024 floats, 256 thr x float4) ----------------
__global__ __launch_bounds__(256) void rmsnorm_k(const float* __restrict__ in, const float* __restrict__ w,
                                                 float* __restrict__ out){
  __shared__ float sb[4];
  size_t r = blockIdx.x;
  float4 x = ((const float4*)(in + r*HDIM))[threadIdx.x];
  float ss = block_sum256(x.x*x.x + x.y*x.y + x.z*x.z + x.w*x.w, sb);
  float sc = 1.0f / sqrtf(ss*(1.0f/HDIM) + EPSF);
  float4 wv = ((const float4*)w)[threadIdx.x];
  ((float4*)(out + r*HDIM))[threadIdx.x] =
      make_float4(x.x*sc*wv.x, x.y*sc*wv.y, x.z*sc*wv.z, x.w*sc*wv.w);
}

// y = ys * silu(z);  out = rmsnorm(y) * w      (z = proj[:, 0:1024])
__global__ __launch_bounds__(256) void gated_rmsnorm_k(const float* __restrict__ ys, const float* __restrict__ proj,
                                                       const float* __restrict__ w, float* __restrict__ out){
  __shared__ float sb[4];
  size_t r = blockIdx.x;
  float4 y = ((const float4*)(ys + r*MINTN))[threadIdx.x];
  float4 z = ((const float4*)(proj + r*DPROJ))[threadIdx.x];
  y.x *= siluf(z.x); y.y *= siluf(z.y); y.z *= siluf(z.z); y.w *= siluf(z.w);
  float ss = block_sum256(y.x*y.x + y.y*y.y + y.z*y.z + y.w*y.w, sb);
  float sc = 1.0f / sqrtf(ss*(1.0f/MINTN) + EPSF);
  float4 wv = ((const float4*)w)[threadIdx.x];
  ((float4*)(out + r*MINTN))[threadIdx.x] =
      make_float4(y.x*sc*wv.x, y.y*sc*wv.y, y.z*sc*wv.z, y.w*sc*wv.w);
}

// ---------------- fp32 tiled GEMM: C[M,N] = A[M,K] @ B[K,N] (+epilogue) ----------------
// BM=128 BN=64 BK=16, 256 threads, 8x4 micro-tile.
// EPI: 0 none, 1 +=bias[n], 2 +=extra[m,n]
template<int EPI>
__global__ __launch_bounds__(256) void gemm_k(const float* __restrict__ A, const float* __restrict__ B,
                                              float* __restrict__ C, const float* __restrict__ bias,
                                              const float* __restrict__ extra, int M, int N, int K){
  __shared__ float As[16][132];  // transposed A tile, padded (2-way bank alias max)
  __shared__ float Bs[16][64];
  int tid = threadIdx.x;
  int tx = tid & 15, ty = tid >> 4;
  int m0 = blockIdx.y * 128, n0 = blockIdx.x * 64;
  int ar = tid >> 2, ak = (tid & 3) * 4;   // A: rows ar, ar+64; k-cols ak..ak+3
  int bk = tid >> 4, bn = (tid & 15) * 4;  // B: row bk, cols bn..bn+3
  float acc[8][4];
#pragma unroll
  for (int i = 0; i < 8; i++)
#pragma unroll
    for (int j = 0; j < 4; j++) acc[i][j] = 0.f;

  for (int k0 = 0; k0 < K; k0 += 16){
    float4 a0 = make_float4(0,0,0,0), a1 = make_float4(0,0,0,0), b0 = make_float4(0,0,0,0);
    if (m0 + ar < M)      a0 = *(const float4*)(A + (size_t)(m0+ar)*K + k0 + ak);
    if (m0 + ar + 64 < M) a1 = *(const float4*)(A + (size_t)(m0+ar+64)*K + k0 + ak);
    if (n0 + bn < N)      b0 = *(const float4*)(B + (size_t)(k0+bk)*N + n0 + bn);
    __syncthreads();
    As[ak+0][ar] = a0.x; As[ak+1][ar] = a0.y; As[ak+2][ar] = a0.z; As[ak+3][ar] = a0.w;
    As[ak+0][ar+64] = a1.x; As[ak+1][ar+64] = a1.y; As[ak+2][ar+64] = a1.z; As[ak+3][ar+64] = a1.w;
    *(float4*)&Bs[bk][bn] = b0;
    __syncthreads();
#pragma unroll
    for (int kk = 0; kk < 16; kk++){
      float a[8], b[4];
      *(float4*)(a)   = *(const float4*)&As[kk][ty*8];
      *(float4*)(a+4) = *(const float4*)&As[kk][ty*8+4];
      *(float4*)(b)   = *(const float4*)&Bs[kk][tx*4];
#pragma unroll
      for (int i = 0; i < 8; i++)
#pragma unroll
        for (int j = 0; j < 4; j++) acc[i][j] = fmaf(a[i], b[j], acc[i][j]);
    }
  }
  int n = n0 + tx*4;
  if (n >= N) return;   // N is always a multiple of 4; whole float4 valid or not
#pragma unroll
  for (int i = 0; i < 8; i++){
    int m = m0 + ty*8 + i;
    if (m >= M) break;
    float r0 = acc[i][0], r1 = acc[i][1], r2 = acc[i][2], r3 = acc[i][3];
    if (EPI == 1){ r0 += bias[n]; r1 += bias[n+1]; r2 += bias[n+2]; r3 += bias[n+3]; }
    if (EPI == 2){ const float* e = extra + (size_t)m*N + n; r0 += e[0]; r1 += e[1]; r2 += e[2]; r3 += e[3]; }
    *(float4*)(C + (size_t)m*N + n) = make_float4(r0, r1, r2, r3);
  }
}

// ---------------- fused gate/up GEMM: C = silu(A@G) * (A@U) ----------------
__global__ __launch_bounds__(256) void gemm_gateup_k(const float* __restrict__ A, const float* __restrict__ G,
                                                     const float* __restrict__ U, float* __restrict__ C,
                                                     int M, int N, int K){
  __shared__ float As[16][132];
  __shared__ float Gs[16][64];
  __shared__ float Us[16][64];
  int tid = threadIdx.x;
  int tx = tid & 15, ty = tid >> 4;
  int m0 = blockIdx.y * 128, n0 = blockIdx.x * 64;
  int ar = tid >> 2, ak = (tid & 3) * 4;
  int bk = tid >> 4, bn = (tid & 15) * 4;
  float accg[8][4], accu[8][4];
#pragma unroll
  for (int i = 0; i < 8; i++)
#pragma unroll
    for (int j = 0; j < 4; j++){ accg[i][j] = 0.f; accu[i][j] = 0.f; }

  for (int k0 = 0; k0 < K; k0 += 16){
    float4 a0 = *(const float4*)(A + (size_t)(m0+ar)*K + k0 + ak);
    float4 a1 = *(const float4*)(A + (size_t)(m0+ar+64)*K + k0 + ak);
    float4 g0 = *(const float4*)(G + (size_t)(k0+bk)*N + n0 + bn);
    float4 u0 = *(const float4*)(U + (size_t)(k0+bk)*N + n0 + bn);
    __syncthreads();
    As[ak+0][ar] = a0.x; As[ak+1][ar] = a0.y; As[ak+2][ar] = a0.z; As[ak+3][ar] = a0.w;
    As[ak+0][ar+64] = a1.x; As[ak+1][ar+64] = a1.y; As[ak+2][ar+64] = a1.z; As[ak+3][ar+64] = a1.w;
    *(float4*)&Gs[bk][bn] = g0;
    *(float4*)&Us[bk][bn] = u0;
    __syncthreads();
#pragma unroll
    for (int kk = 0; kk < 16; kk++){
      float a[8], g[4], u[4];
      *(float4*)(a)   = *(const float4*)&As[kk][ty*8];
      *(float4*)(a+4) = *(const float4*)&As[kk][ty*8+4];
      *(float4*)(g)   = *(const float4*)&Gs[kk][tx*4];
      *(float4*)(u)   = *(const float4*)&Us[kk][tx*4];
#pragma unroll
      for (int i = 0; i < 8; i++)
#pragma unroll
        for (int j = 0; j < 4; j++){
          accg[i][j] = fmaf(a[i], g[j], accg[i][j]);
          accu[i][j] = fmaf(a[i], u[j], accu[i][j]);
        }
    }
  }
  int n = n0 + tx*4;
#pragma unroll
  for (int i = 0; i < 8; i++){
    int m = m0 + ty*8 + i;
    *(float4*)(C + (size_t)m*N + n) =
        make_float4(siluf(accg[i][0])*accu[i][0], siluf(accg[i][1])*accu[i][1],
                    siluf(accg[i][2])*accu[i][2], siluf(accg[i][3])*accu[i][3]);
  }
}

// ---------------- causal depthwise conv (K=4) + silu over xBC cols ----------------
__global__ __launch_bounds__(256) void conv_silu_k(const float* __restrict__ proj, const float* __restrict__ cw,
                                                   const float* __restrict__ cb, float* __restrict__ out){
  int idx = blockIdx.x*256 + threadIdx.x;
  if (idx >= LMN*CONVD) return;
  int c = idx % CONVD;
  int t = idx / CONVD;
  float acc = cb[c];
#pragma unroll
  for (int kk = 0; kk < KCONV; kk++){
    int ts = t + kk - (KCONV-1);
    if (ts >= 0) acc = fmaf(proj[(size_t)ts*DPROJ + MINTN + c], cw[c*KCONV + kk], acc);
  }
  out[idx] = siluf(acc);
}

__global__ __launch_bounds__(256) void dtprep_k(const float* __restrict__ proj, const float* __restrict__ dtb,
                                                const float* __restrict__ alog, float* __restrict__ dt,
                                                float* __restrict__ dA){
  int idx = blockIdx.x*256 + threadIdx.x;
  if (idx >= LMN*NHEAD) return;
  int h = idx & 15, t = idx >> 4;
  float d = softplusf_(proj[(size_t)t*DPROJ + MINTN + CONVD + h] + dtb[h]);
  dt[idx] = d;
  dA[idx] = expf(-d * expf(alog[h]));
}

// ================= 3-pass chunked SSM scan =================
// Serial depth 1664 -> 128 (pass1, parallel over 13 chunks) + 13 (pass2) + 128 (pass3).
// Block map for passes 1&3: blockIdx = c*64 + h*4 + dgroup; 256 thr = 16 d x 16 nc.
// hloc layout: [c][h][n][d] (n = nc*16+i), i.e. ((c*16+h)*256 + n)*64 + d.

// pass 2 helper: aQ[c][h] = prod of dA over chunk c. 208 blocks x 64 lanes, wave multiply-reduce.
__global__ __launch_bounds__(64) void chunk_prod_k(const float* __restrict__ dAb, float* __restrict__ aQ){
  int c = blockIdx.x >> 4, h = blockIdx.x & 15;
  int lane = threadIdx.x;
  float p = dAb[(c*SCHUNK + lane)*NHEAD + h] * dAb[(c*SCHUNK + 64 + lane)*NHEAD + h];
#pragma unroll
  for (int m = 32; m > 0; m >>= 1) p *= __shfl_xor(p, m);
  if (lane == 0) aQ[c*NHEAD + h] = p;
}

// pass 1: local end-state of each chunk starting from 0 (no y, no C)
__global__ __launch_bounds__(256) void scan_local_k(const float* __restrict__ cv, const float* __restrict__ dtb,
                                                    const float* __restrict__ dAb, float* __restrict__ hloc){
  int c = blockIdx.x >> 6;
  int sub = blockIdx.x & 63;
  int h = sub >> 2;
  int d = (sub & 3)*16 + (threadIdx.x >> 4);
  int nc = threadIdx.x & 15;
  int g = h >> 2;
  const float* xp = cv + h*HEADD + d;
  const float* Bp = cv + MINTN + g*STATEN + nc*16;
  int t0 = c*SCHUNK;
  float s[16];
#pragma unroll
  for (int i = 0; i < 16; i++) s[i] = 0.f;

  float4 B0[4], B1[4];
  float x0, dt0, dA0, x1, dt1, dA1;
  {
    size_t o = (size_t)t0*CONVD;
    x0 = xp[o]; dt0 = dtb[t0*NHEAD + h]; dA0 = dAb[t0*NHEAD + h];
    B0[0]=((const float4*)(Bp+o))[0]; B0[1]=((const float4*)(Bp+o))[1];
    B0[2]=((const float4*)(Bp+o))[2]; B0[3]=((const float4*)(Bp+o))[3];
    o = (size_t)(t0+1)*CONVD;
    x1 = xp[o]; dt1 = dtb[(t0+1)*NHEAD + h]; dA1 = dAb[(t0+1)*NHEAD + h];
    B1[0]=((const float4*)(Bp+o))[0]; B1[1]=((const float4*)(Bp+o))[1];
    B1[2]=((const float4*)(Bp+o))[2]; B1[3]=((const float4*)(Bp+o))[3];
  }
  for (int tt = 0; tt < SCHUNK; tt += 2){
    {
      float coef = dt0 * x0;
      const float* bf = (const float*)B0;
#pragma unroll
      for (int i = 0; i < 16; i++) s[i] = fmaf(s[i], dA0, coef*bf[i]);
      int tn = t0 + ((tt+2 < SCHUNK) ? tt+2 : SCHUNK-1);
      size_t o = (size_t)tn*CONVD;
      x0 = xp[o]; dt0 = dtb[tn*NHEAD + h]; dA0 = dAb[tn*NHEAD + h];
      B0[0]=((const float4*)(Bp+o))[0]; B0[1]=((const float4*)(Bp+o))[1];
      B0[2]=((const float4*)(Bp+o))[2]; B0[3]=((const float4*)(Bp+o))[3];
    }
    {
      float coef = dt1 * x1;
      const float* bf = (const float*)B1;
#pragma unroll
      for (int i = 0; i < 16; i++) s[i] = fmaf(s[i], dA1, coef*bf[i]);
      int tn = t0 + ((tt+3 < SCHUNK) ? tt+3 : SCHUNK-1);
      size_t o = (size_t)tn*CONVD;
      x1 = xp[o]; dt1 = dtb[tn*NHEAD + h]; dA1 = dAb[tn*NHEAD + h];
      B1[0]=((const float4*)(Bp+o))[0]; B1[1]=((const float4*)(Bp+o))[1];
      B1[2]=((const float4*)(Bp+o))[2]; B1[3]=((const float4*)(Bp+o))[3];
    }
  }
  size_t base = ((size_t)(c*NHEAD + h)*STATEN + nc*16)*64 + d;
#pragma unroll
  for (int i = 0; i < 16; i++) hloc[base + (size_t)i*64] = s[i];
}

// pass 2: in-place convert hloc[c] -> entry state H_start[c]
__global__ __launch_bounds__(256) void chunk_combine_k(float* __restrict__ hloc, const float* __restrict__ aQ){
  int e = blockIdx.x*256 + threadIdx.x;      // 16*256*64 = 262144 elements
  int h = e >> 14;
  float s = 0.f;
  for (int c = 0; c < NCHUNK; c++){
    float a = aQ[c*NHEAD + h];
    size_t off = (size_t)c*(NHEAD*STATEN*64) + e;
    float tmp = hloc[off];
    hloc[off] = s;
    s = fmaf(s, a, tmp);
  }
}

// pass 3: full scan within chunk from entry state, emitting y
__global__ __launch_bounds__(256) void scan_out_k(const float* __restrict__ cv, const float* __restrict__ dtb,
                                                  const float* __restrict__ dAb, const float* __restrict__ Dp,
                                                  const float* __restrict__ hstart, float* __restrict__ ys){
  int c = blockIdx.x >> 6;
  int sub = blockIdx.x & 63;
  int h = sub >> 2;
  int d = (sub & 3)*16 + (threadIdx.x >> 4);
  int nc = threadIdx.x & 15;
  int g = h >> 2;
  const float* xp = cv + h*HEADD + d;
  const float* Bp = cv + MINTN + g*STATEN + nc*16;
  const float* Cp = cv + MINTN + 1024 + g*STATEN + nc*16;
  float Dh = Dp[h];
  int t0 = c*SCHUNK;
  float s[16];
  {
    size_t base = ((size_t)(c*NHEAD + h)*STATEN + nc*16)*64 + d;
#pragma unroll
    for (int i = 0; i < 16; i++) s[i] = hstart[base + (size_t)i*64];
  }

  float4 B0[4], C0[4], B1[4], C1[4];
  float x0, dt0, dA0, x1, dt1, dA1;
  {
    size_t o = (size_t)t0*CONVD;
    x0 = xp[o]; dt0 = dtb[t0*NHEAD + h]; dA0 = dAb[t0*NHEAD + h];
    B0[0]=((const float4*)(Bp+o))[0]; B0[1]=((const float4*)(Bp+o))[1];
    B0[2]=((const float4*)(Bp+o))[2]; B0[3]=((const float4*)(Bp+o))[3];
    C0[0]=((const float4*)(Cp+o))[0]; C0[1]=((const float4*)(Cp+o))[1];
    C0[2]=((const float4*)(Cp+o))[2]; C0[3]=((const float4*)(Cp+o))[3];
    o = (size_t)(t0+1)*CONVD;
    x1 = xp[o]; dt1 = dtb[(t0+1)*NHEAD + h]; dA1 = dAb[(t0+1)*NHEAD + h];
    B1[0]=((const float4*)(Bp+o))[0]; B1[1]=((const float4*)(Bp+o))[1];
    B1[2]=((const float4*)(Bp+o))[2]; B1[3]=((const float4*)(Bp+o))[3];
    C1[0]=((const float4*)(Cp+o))[0]; C1[1]=((const float4*)(Cp+o))[1];
    C1[2]=((const float4*)(Cp+o))[2]; C1[3]=((const float4*)(Cp+o))[3];
  }
  for (int tt = 0; tt < SCHUNK; tt += 2){
    {
      int t = t0 + tt;
      float coef = dt0 * x0;
      float accp[4] = {0.f,0.f,0.f,0.f};
      const float* bf = (const float*)B0;
      const float* cf = (const float*)C0;
#pragma unroll
      for (int i = 0; i < 16; i++){
        s[i] = fmaf(s[i], dA0, coef*bf[i]);
        accp[i & 3] = fmaf(s[i], cf[i], accp[i & 3]);
      }
      float accv = (accp[0]+accp[1])+(accp[2]+accp[3]);
      accv += __shfl_xor(accv, 1); accv += __shfl_xor(accv, 2);
      accv += __shfl_xor(accv, 4); accv += __shfl_xor(accv, 8);
      if (nc == 0) ys[(size_t)t*MINTN + h*HEADD + d] = accv + Dh*x0;
      int tn = t0 + ((tt+2 < SCHUNK) ? tt+2 : SCHUNK-1);
      size_t o = (size_t)tn*CONVD;
      x0 = xp[o]; dt0 = dtb[tn*NHEAD + h]; dA0 = dAb[tn*NHEAD + h];
      B0[0]=((const float4*)(Bp+o))[0]; B0[1]=((const float4*)(Bp+o))[1];
      B0[2]=((const float4*)(Bp+o))[2]; B0[3]=((const float4*)(Bp+o))[3];
      C0[0]=((const float4*)(Cp+o))[0]; C0[1]=((const float4*)(Cp+o))[1];
      C0[2]=((const float4*)(Cp+o))[2]; C0[3]=((const float4*)(Cp+o))[3];
    }
    {
      int t = t0 + tt + 1;
      float coef = dt1 * x1;
      float accp[4] = {0.f,0.f,0.f,0.f};
      const float* bf = (const float*)B1;
      const float* cf = (const float*)C1;
#pragma unroll
      for (int i = 0; i < 16; i++){
        s[i] = fmaf(s[i], dA1, coef*bf[i]);
        accp[i & 3] = fmaf(s[i], cf[i], accp[i & 3]);
      }
      float accv = (accp[0]+accp[1])+(accp[2]+accp[3]);
      accv += __shfl_xor(accv, 1); accv += __shfl_xor(accv, 2);
      accv += __shfl_xor(accv, 4); accv += __shfl_xor(accv, 8);
      if (nc == 0) ys[(size_t)t*MINTN + h*HEADD + d] = accv + Dh*x1;
      int tn = t0 + ((tt+3 < SCHUNK) ? tt+3 : SCHUNK-1);
      size_t o = (size_t)tn*CONVD;
      x1 = xp[o]; dt1 = dtb[tn*NHEAD + h]; dA1 = dAb[tn*NHEAD + h];
      B1[0]=((const float4*)(Bp+o))[0]; B1[1]=((const float4*)(Bp+o))[1];
      B1[2]=((const float4*)(Bp+o))[2]; B1[3]=((const float4*)(Bp+o))[3];
      C1[0]=((const float4*)(Cp+o))[0]; C1[1]=((const float4*)(Cp+o))[1];
      C1[2]=((const float4*)(Cp+o))[2]; C1[3]=((const float4*)(Cp+o))[3];
    }
  }
}

// ---------------- small assembly kernels ----------------
__global__ __launch_bounds__(256) void build_hc_k(const float* __restrict__ hn, const float* __restrict__ memo,
                                                  float* __restrict__ hc){
  int idx = blockIdx.x*256 + threadIdx.x;
  if (idx >= TCN*HDIM) return;
  int r = idx >> 10, c = idx & 1023;
  float v;
  if (r < SINKN)        v = hn[(size_t)r*HDIM + c];
  else if (r == SINKN)  v = memo[(size_t)(LMN-1)*HDIM + c];
  else                  v = hn[(size_t)(r + 1663)*HDIM + c];
  hc[idx] = v;
}

__global__ __launch_bounds__(256) void rope_k(float* __restrict__ q, float* __restrict__ k,
                                              const float* __restrict__ cosp, const float* __restrict__ sinp){
  int idx = blockIdx.x*256 + threadIdx.x;
  if (idx >= TCN*20*32) return;
  int dd = idx & 31;
  int hh = (idx >> 5) % 20;
  int t  = idx / (20*32);
  int ci = (t <= SINKN) ? t : t + 1663;
  float* p = (hh < NHEAD) ? (q + (size_t)t*HDIM + hh*HEADD)
                          : (k + (size_t)t*(NKVH*HEADD) + (hh - NHEAD)*HEADD);
  float a = p[dd], b = p[dd+32];
  float c0 = cosp[(size_t)ci*HEADD + dd], c1 = cosp[(size_t)ci*HEADD + dd + 32];
  float s0 = sinp[(size_t)ci*HEADD + dd], s1 = sinp[(size_t)ci*HEADD + dd + 32];
  p[dd]    = a*c0 - b*s0;
  p[dd+32] = b*c1 + a*s1;
}

// ---------------- flash-style fp32 attention, Tc=385, causal, GQA 16q/4kv ----------------
__global__ __launch_bounds__(256) void attn_k(const float* __restrict__ q, const float* __restrict__ k,
                                              const float* __restrict__ v, float* __restrict__ aoc){
  __shared__ float Qs[64][65];   // Q tile; reused as P tile after hoist
  __shared__ float Ks[64][65];
  __shared__ float Vs[64][68];
  int qt = blockIdx.x, h = blockIdx.y;
  int tid = threadIdx.x;
  int ql = tid >> 2, dg = tid & 3;
  int qg = qt*64 + ql;
  int kvh = h >> 2;
#pragma unroll
  for (int i = 0; i < 16; i++){
    int idx = tid + 256*i;
    int r = idx >> 6, c = idx & 63;
    int qr = qt*64 + r;
    Qs[r][c] = (qr < TCN) ? q[(size_t)qr*HDIM + h*HEADD + c] : 0.f;
  }
  __syncthreads();
  float qreg[64];
#pragma unroll
  for (int d2 = 0; d2 < 64; d2++) qreg[d2] = Qs[ql][d2];
  __syncthreads();  // Qs is reused as P storage below

  float mrun = -INFINITY, lrun = 0.f;
  float acc[16];
#pragma unroll
  for (int i = 0; i < 16; i++) acc[i] = 0.f;

  for (int kt = 0; kt <= qt; kt++){
    __syncthreads();
#pragma unroll
    for (int i = 0; i < 16; i++){
      int idx = tid + 256*i;
      int r = idx >> 6, c = idx & 63;
      int kr = kt*64 + r;
      float kv = 0.f, vv = 0.f;
      if (kr < TCN){
        kv = k[(size_t)kr*(NKVH*HEADD) + kvh*HEADD + c];
        vv = v[(size_t)kr*(NKVH*HEADD) + kvh*HEADD + c];
      }
      Ks[r][c] = kv; Vs[r][c] = vv;
    }
    __syncthreads();
    float p[16]; float tmax = -INFINITY;
#pragma unroll
    for (int jj = 0; jj < 16; jj++){
      int j = jj*4 + dg;            // key-interleave keeps LDS banks conflict-free
      float sv = 0.f;
#pragma unroll
      for (int d2 = 0; d2 < 64; d2++) sv = fmaf(qreg[d2], Ks[j][d2], sv);
      sv *= 0.125f;                  // HD^-0.5
      int kr = kt*64 + j;
      if (kr > qg || kr >= TCN) sv = -INFINITY;
      p[jj] = sv;
      tmax = fmaxf(tmax, sv);
    }
    tmax = fmaxf(tmax, __shfl_xor(tmax, 1));
    tmax = fmaxf(tmax, __shfl_xor(tmax, 2));
    float nm = fmaxf(mrun, tmax);
    if (nm == -INFINITY) nm = 0.f;  // fully-masked rows: avoid NaN
    float sc = expf(mrun - nm);
    float sump = 0.f;
#pragma unroll
    for (int jj = 0; jj < 16; jj++){ p[jj] = expf(p[jj] - nm); sump += p[jj]; }
    sump += __shfl_xor(sump, 1);
    sump += __shfl_xor(sump, 2);
    lrun = lrun*sc + sump;
    mrun = nm;
#pragma unroll
    for (int i = 0; i < 16; i++) acc[i] *= sc;
#pragma unroll
    for (int jj = 0; jj < 16; jj++) Qs[ql][jj*4 + dg] = p[jj];
    __syncthreads();
#pragma unroll
    for (int j = 0; j < 64; j++){
      float pv = Qs[ql][j];
#pragma unroll
      for (int c4 = 0; c4 < 4; c4++){
        float4 vv = *(const float4*)&Vs[j][dg*16 + c4*4];
        acc[c4*4+0] = fmaf(pv, vv.x, acc[c4*4+0]);
        acc[c4*4+1] = fmaf(pv, vv.y, acc[c4*4+1]);
        acc[c4*4+2] = fmaf(pv, vv.z, acc[c4*4+2]);
        acc[c4*4+3] = fmaf(pv, vv.w, acc[c4*4+3]);
      }
    }
  }
  if (qg < TCN){
    float inv = 1.0f / lrun;
#pragma unroll
    for (int c4 = 0; c4 < 4; c4++){
      *(float4*)(aoc + (size_t)qg*HDIM + h*HEADD + dg*16 + c4*4) =
          make_float4(acc[c4*4]*inv, acc[c4*4+1]*inv, acc[c4*4+2]*inv, acc[c4*4+3]*inv);
    }
  }
}

__global__ __launch_bounds__(256) void build_ao_k(const float* __restrict__ aoc, const float* __restrict__ memo,
                                                  float* __restrict__ aof){
  int idx = blockIdx.x*256 + threadIdx.x;
  if (idx >= TLEN*HDIM) return;
  int r = idx >> 10, c = idx & 1023;
  float v;
  if (r < SINKN)              v = aoc[(size_t)r*HDIM + c];
  else if (r < TLEN - WINN)   v = memo[(size_t)(r - SINKN)*HDIM + c];
  else                        v = aoc[(size_t)(r - 1663)*HDIM + c];
  aof[idx] = v;
}

extern "C" void kernel_launch(void* const* d_in, const int* in_sizes, int n_in,
                              void* d_out, int out_size, void* d_ws, size_t ws_size,
                              hipStream_t stream){
  (void)in_sizes; (void)n_in; (void)out_size; (void)ws_size;
  const float* x      = (const float*)d_in[0];
  const float* cosp   = (const float*)d_in[1];
  const float* sinp   = (const float*)d_in[2];
  const float* ln1_w  = (const float*)d_in[3];
  const float* q_w    = (const float*)d_in[4];
  const float* q_b    = (const float*)d_in[5];
  const float* k_w    = (const float*)d_in[6];
  const float* k_b    = (const float*)d_in[7];
  const float* v_w    = (const float*)d_in[8];
  const float* v_b    = (const float*)d_in[9];
  const float* o_w    = (const float*)d_in[10];
  const float* inpw   = (const float*)d_in[11];
  const float* convw  = (const float*)d_in[12];
  const float* convb  = (const float*)d_in[13];
  const float* dtbias = (const float*)d_in[14];
  const float* alog   = (const float*)d_in[15];
  const float* Dp     = (const float*)d_in[16];
  const float* mnw    = (const float*)d_in[17];
  const float* moutw  = (const float*)d_in[18];
  const float* ln2_w  = (const float*)d_in[19];
  const float* gatew  = (const float*)d_in[20];
  const float* upw    = (const float*)d_in[21];
  const float* downw  = (const float*)d_in[22];
  float* out = (float*)d_out;

  // Workspace overlay (floats). Peak = 19,216,592 floats = 73.3 MiB.
  //   hn    @0           live 1-8 ; h1 reuses @0 (15-18)
  //   proj  @2,097,152   live 2-6 ; aof (14-15) / mlpin (16-17) reuse front; gu @4,194,304 (17-18)
  //   conv  @8,939,520   live 3-5 ; memo (7-14) / mamx (6-7) reuse
  //   dtb   @14,051,328  live 4-5 ; dAb @14,077,952
  //   yscan @14,104,576  live 5-6 ; hc/qb/kb/vb/aoc reuse after
  //   hloc  @15,808,512  (3,407,872) live scan passes only
  //   aQ    @19,216,384  (208)
  float* w     = (float*)d_ws;
  float* hn    = w + 0;
  float* proj  = w + 2097152;
  float* conv  = w + 8939520;
  float* memo  = w + 8939520;
  float* mamx  = w + 10643456;
  float* dtb   = w + 14051328;
  float* dAb   = w + 14077952;
  float* yscan = w + 14104576;
  float* hc    = w + 14104576;
  float* qb    = w + 14498816;
  float* kb    = w + 14893056;
  float* vb    = w + 14991616;
  float* aoc   = w + 15090176;
  float* hloc  = w + 15808512;
  float* aQ    = w + 19216384;
  float* aof   = w + 2097152;
  float* h1    = w + 0;
  float* mlpin = w + 2097152;
  float* gu    = w + 4194304;

  // 1. ln1
  rmsnorm_k<<<TLEN, 256, 0, stream>>>(x, ln1_w, hn);
  // 2. mamba in_proj on evicted rows [128,1792)
  gemm_k<0><<<dim3(65, 13), 256, 0, stream>>>(hn + (size_t)SINKN*HDIM, inpw, proj, nullptr, nullptr, LMN, DPROJ, HDIM);
  // 3. conv + silu
  conv_silu_k<<<(LMN*CONVD + 255)/256, 256, 0, stream>>>(proj, convw, convb, conv);
  // 4. dt = softplus(dt+bias), dA = exp(dt*A)
  dtprep_k<<<(LMN*NHEAD + 255)/256, 256, 0, stream>>>(proj, dtbias, alog, dtb, dAb);
  // 5. chunked scan: chunk decay -> local states -> combine -> outputs
  chunk_prod_k<<<NCHUNK*NHEAD, 64, 0, stream>>>(dAb, aQ);
  scan_local_k<<<NCHUNK*64, 256, 0, stream>>>(conv, dtb, dAb, hloc);
  chunk_combine_k<<<1024, 256, 0, stream>>>(hloc, aQ);
  scan_out_k<<<NCHUNK*64, 256, 0, stream>>>(conv, dtb, dAb, Dp, hloc, yscan);
  // 6. gate by silu(z), rmsnorm
  gated_rmsnorm_k<<<LMN, 256, 0, stream>>>(yscan, proj, mnw, mamx);
  // 7. mamba out proj
  gemm_k<0><<<dim3(16, 13), 256, 0, stream>>>(mamx, moutw, memo, nullptr, nullptr, LMN, HDIM, HDIM);
  // 8. compressed sequence hc (385 tokens)
  build_hc_k<<<(TCN*HDIM + 255)/256, 256, 0, stream>>>(hn, memo, hc);
  // 9-11. qkv projections (+bias)
  gemm_k<1><<<dim3(16, 4), 256, 0, stream>>>(hc, q_w, qb, q_b, nullptr, TCN, HDIM, HDIM);
  gemm_k<1><<<dim3(4, 4), 256, 0, stream>>>(hc, k_w, kb, k_b, nullptr, TCN, NKVH*HEADD, HDIM);
  gemm_k<1><<<dim3(4, 4), 256, 0, stream>>>(hc, v_w, vb, v_b, nullptr, TCN, NKVH*HEADD, HDIM);
  // 12. rope on q,k (concatenated cos/sin indexing)
  rope_k<<<(TCN*20*32 + 255)/256, 256, 0, stream>>>(qb, kb, cosp, sinp);
  // 13. causal attention
  attn_k<<<dim3(7, 16), 256, 0, stream>>>(qb, kb, vb, aoc);
  // 14. splice mem_out back into full-length ao
  build_ao_k<<<(TLEN*HDIM + 255)/256, 256, 0, stream>>>(aoc, memo, aof);
  // 15. o_proj + residual x -> h1
  gemm_k<2><<<dim3(16, 16), 256, 0, stream>>>(aof, o_w, h1, nullptr, x, TLEN, HDIM, HDIM);
  // 16. ln2
  rmsnorm_k<<<TLEN, 256, 0, stream>>>(h1, ln2_w, mlpin);
  // 17. fused gate/up proj: gu = silu(mlpin@gate_w) * (mlpin@up_w)
  gemm_gateup_k<<<dim3(64, 16), 256, 0, stream>>>(mlpin, gatew, upw, gu, TLEN, INTERN, HDIM);
  // 18. down proj + residual h1 -> out
  gemm_k<2><<<dim3(16, 16), 256, 0, stream>>>(gu, downw, out, nullptr, h1, TLEN, HDIM, INTERN);
}

// Round 8
// 2005.638 us; speedup vs baseline: 1.9563x; 1.1243x over previous
//
#include <hip/hip_runtime.h>
#include <hip/hip_bf16.h>
#include <math.h>

#define TLEN 2048
#define HDIM 1024
#define NHEAD 16
#define HEADD 64
#define NKVH 4
#define SINKN 128
#define WINN 256
#define STATEN 256
#define KCONV 4
#define MINTN 1024
#define CONVD 3072
#define DPROJ 4112
#define INTERN 4096
#define LMN 1664
#define TCN 385
#define EPSF 1e-6f
#define SCHUNK 128
#define NCHUNK 13   /* 13*128 = 1664 */

__device__ __forceinline__ float siluf(float x){ return x / (1.0f + expf(-x)); }
__device__ __forceinline__ float softplusf_(float x){ return fmaxf(x, 0.0f) + log1pf(expf(-fabsf(x))); }

__device__ __forceinline__ float block_sum256(float v, float* sb){
#pragma unroll
  for (int m = 32; m > 0; m >>= 1) v += __shfl_xor(v, m);
  int wid = threadIdx.x >> 6;
  if ((threadIdx.x & 63) == 0) sb[wid] = v;
  __syncthreads();
  return sb[0] + sb[1] + sb[2] + sb[3];
}

// ---------------- rmsnorm (row = 1024 floats, 256 thr x float4) ----------------
__global__ __launch_bounds__(256) void rmsnorm_k(const float* __restrict__ in, const float* __restrict__ w,
                                                 float* __restrict__ out){
  __shared__ float sb[4];
  size_t r = blockIdx.x;
  float4 x = ((const float4*)(in + r*HDIM))[threadIdx.x];
  float ss = block_sum256(x.x*x.x + x.y*x.y + x.z*x.z + x.w*x.w, sb);
  float sc = 1.0f / sqrtf(ss*(1.0f/HDIM) + EPSF);
  float4 wv = ((const float4*)w)[threadIdx.x];
  ((float4*)(out + r*HDIM))[threadIdx.x] =
      make_float4(x.x*sc*wv.x, x.y*sc*wv.y, x.z*sc*wv.z, x.w*sc*wv.w);
}

// y = ys * silu(z);  out = rmsnorm(y) * w      (z = proj[:, 0:1024])
__global__ __launch_bounds__(256) void gated_rmsnorm_k(const float* __restrict__ ys, const float* __restrict__ proj,
                                                       const float* __restrict__ w, float* __restrict__ out){
  __shared__ float sb[4];
  size_t r = blockIdx.x;
  float4 y = ((const float4*)(ys + r*MINTN))[threadIdx.x];
  float4 z = ((const float4*)(proj + r*DPROJ))[threadIdx.x];
  y.x *= siluf(z.x); y.y *= siluf(z.y); y.z *= siluf(z.z); y.w *= siluf(z.w);
  float ss = block_sum256(y.x*y.x + y.y*y.y + y.z*y.z + y.w*y.w, sb);
  float sc = 1.0f / sqrtf(ss*(1.0f/MINTN) + EPSF);
  float4 wv = ((const float4*)w)[threadIdx.x];
  ((float4*)(out + r*MINTN))[threadIdx.x] =
      make_float4(y.x*sc*wv.x, y.y*sc*wv.y, y.z*sc*wv.z, y.w*sc*wv.w);
}

// ---------------- fp32 tiled GEMM: C[M,N] = A[M,K] @ B[K,N] (+epilogue) ----------------
// BM=128 BN=64 BK=16, 256 threads, 8x4 micro-tile. For LARGE grids (in_proj).
// EPI: 0 none, 1 +=bias[n], 2 +=extra[m,n]
template<int EPI>
__global__ __launch_bounds__(256) void gemm_k(const float* __restrict__ A, const float* __restrict__ B,
                                              float* __restrict__ C, const float* __restrict__ bias,
                                              const float* __restrict__ extra, int M, int N, int K){
  __shared__ float As[16][132];  // transposed A tile, padded (2-way bank alias max)
  __shared__ float Bs[16][64];
  int tid = threadIdx.x;
  int tx = tid & 15, ty = tid >> 4;
  int m0 = blockIdx.y * 128, n0 = blockIdx.x * 64;
  int ar = tid >> 2, ak = (tid & 3) * 4;   // A: rows ar, ar+64; k-cols ak..ak+3
  int bk = tid >> 4, bn = (tid & 15) * 4;  // B: row bk, cols bn..bn+3
  float acc[8][4];
#pragma unroll
  for (int i = 0; i < 8; i++)
#pragma unroll
    for (int j = 0; j < 4; j++) acc[i][j] = 0.f;

  for (int k0 = 0; k0 < K; k0 += 16){
    float4 a0 = make_float4(0,0,0,0), a1 = make_float4(0,0,0,0), b0 = make_float4(0,0,0,0);
    if (m0 + ar < M)      a0 = *(const float4*)(A + (size_t)(m0+ar)*K + k0 + ak);
    if (m0 + ar + 64 < M) a1 = *(const float4*)(A + (size_t)(m0+ar+64)*K + k0 + ak);
    if (n0 + bn < N)      b0 = *(const float4*)(B + (size_t)(k0+bk)*N + n0 + bn);
    __syncthreads();
    As[ak+0][ar] = a0.x; As[ak+1][ar] = a0.y; As[ak+2][ar] = a0.z; As[ak+3][ar] = a0.w;
    As[ak+0][ar+64] = a1.x; As[ak+1][ar+64] = a1.y; As[ak+2][ar+64] = a1.z; As[ak+3][ar+64] = a1.w;
    *(float4*)&Bs[bk][bn] = b0;
    __syncthreads();
#pragma unroll
    for (int kk = 0; kk < 16; kk++){
      float a[8], b[4];
      *(float4*)(a)   = *(const float4*)&As[kk][ty*8];
      *(float4*)(a+4) = *(const float4*)&As[kk][ty*8+4];
      *(float4*)(b)   = *(const float4*)&Bs[kk][tx*4];
#pragma unroll
      for (int i = 0; i < 8; i++)
#pragma unroll
        for (int j = 0; j < 4; j++) acc[i][j] = fmaf(a[i], b[j], acc[i][j]);
    }
  }
  int n = n0 + tx*4;
  if (n >= N) return;   // N is always a multiple of 4; whole float4 valid or not
#pragma unroll
  for (int i = 0; i < 8; i++){
    int m = m0 + ty*8 + i;
    if (m >= M) break;
    float r0 = acc[i][0], r1 = acc[i][1], r2 = acc[i][2], r3 = acc[i][3];
    if (EPI == 1){ r0 += bias[n]; r1 += bias[n+1]; r2 += bias[n+2]; r3 += bias[n+3]; }
    if (EPI == 2){ const float* e = extra + (size_t)m*N + n; r0 += e[0]; r1 += e[1]; r2 += e[2]; r3 += e[3]; }
    *(float4*)(C + (size_t)m*N + n) = make_float4(r0, r1, r2, r3);
  }
}

// ---------------- fp32 GEMM, 64x64 tile for SMALL grids (down/o_proj/mout/qkv) ----------------
// BM=64 BN=64 BK=16, 256 threads, 4x4 micro-tile: 2x-4x the blocks of the 128-tile
// version -> 2+ blocks/CU -> 8+ waves/CU hides LDS latency (R5: down GEMM was 1
// block/CU, 4 waves, VALUBusy 32%).
template<int EPI>
__global__ __launch_bounds__(256) void gemm64_k(const float* __restrict__ A, const float* __restrict__ B,
                                                float* __restrict__ C, const float* __restrict__ bias,
                                                const float* __restrict__ extra, int M, int N, int K){
  __shared__ float As[16][68];   // transposed A tile, padded
  __shared__ float Bs[16][64];
  int tid = threadIdx.x;
  int tx = tid & 15, ty = tid >> 4;
  int m0 = blockIdx.y * 64, n0 = blockIdx.x * 64;
  int ar = tid >> 2, ak = (tid & 3) * 4;   // A: row ar, k-cols ak..ak+3
  int bk = tid >> 4, bn = (tid & 15) * 4;  // B: row bk, cols bn..bn+3
  float acc[4][4];
#pragma unroll
  for (int i = 0; i < 4; i++)
#pragma unroll
    for (int j = 0; j < 4; j++) acc[i][j] = 0.f;

  for (int k0 = 0; k0 < K; k0 += 16){
    float4 a0 = make_float4(0,0,0,0);
    if (m0 + ar < M) a0 = *(const float4*)(A + (size_t)(m0+ar)*K + k0 + ak);
    float4 b0 = *(const float4*)(B + (size_t)(k0+bk)*N + n0 + bn);  // N multiple of 64
    __syncthreads();
    As[ak+0][ar] = a0.x; As[ak+1][ar] = a0.y; As[ak+2][ar] = a0.z; As[ak+3][ar] = a0.w;
    *(float4*)&Bs[bk][bn] = b0;
    __syncthreads();
#pragma unroll
    for (int kk = 0; kk < 16; kk++){
      float a[4], b[4];
      *(float4*)(a) = *(const float4*)&As[kk][ty*4];
      *(float4*)(b) = *(const float4*)&Bs[kk][tx*4];
#pragma unroll
      for (int i = 0; i < 4; i++)
#pragma unroll
        for (int j = 0; j < 4; j++) acc[i][j] = fmaf(a[i], b[j], acc[i][j]);
    }
  }
  int n = n0 + tx*4;
#pragma unroll
  for (int i = 0; i < 4; i++){
    int m = m0 + ty*4 + i;
    if (m >= M) break;
    float r0 = acc[i][0], r1 = acc[i][1], r2 = acc[i][2], r3 = acc[i][3];
    if (EPI == 1){ r0 += bias[n]; r1 += bias[n+1]; r2 += bias[n+2]; r3 += bias[n+3]; }
    if (EPI == 2){ const float* e = extra + (size_t)m*N + n; r0 += e[0]; r1 += e[1]; r2 += e[2]; r3 += e[3]; }
    *(float4*)(C + (size_t)m*N + n) = make_float4(r0, r1, r2, r3);
  }
}

// ---------------- fused gate/up GEMM: C = silu(A@G) * (A@U) ----------------
__global__ __launch_bounds__(256) void gemm_gateup_k(const float* __restrict__ A, const float* __restrict__ G,
                                                     const float* __restrict__ U, float* __restrict__ C,
                                                     int M, int N, int K){
  __shared__ float As[16][132];
  __shared__ float Gs[16][64];
  __shared__ float Us[16][64];
  int tid = threadIdx.x;
  int tx = tid & 15, ty = tid >> 4;
  int m0 = blockIdx.y * 128, n0 = blockIdx.x * 64;
  int ar = tid >> 2, ak = (tid & 3) * 4;
  int bk = tid >> 4, bn = (tid & 15) * 4;
  float accg[8][4], accu[8][4];
#pragma unroll
  for (int i = 0; i < 8; i++)
#pragma unroll
    for (int j = 0; j < 4; j++){ accg[i][j] = 0.f; accu[i][j] = 0.f; }

  for (int k0 = 0; k0 < K; k0 += 16){
    float4 a0 = *(const float4*)(A + (size_t)(m0+ar)*K + k0 + ak);
    float4 a1 = *(const float4*)(A + (size_t)(m0+ar+64)*K + k0 + ak);
    float4 g0 = *(const float4*)(G + (size_t)(k0+bk)*N + n0 + bn);
    float4 u0 = *(const float4*)(U + (size_t)(k0+bk)*N + n0 + bn);
    __syncthreads();
    As[ak+0][ar] = a0.x; As[ak+1][ar] = a0.y; As[ak+2][ar] = a0.z; As[ak+3][ar] = a0.w;
    As[ak+0][ar+64] = a1.x; As[ak+1][ar+64] = a1.y; As[ak+2][ar+64] = a1.z; As[ak+3][ar+64] = a1.w;
    *(float4*)&Gs[bk][bn] = g0;
    *(float4*)&Us[bk][bn] = u0;
    __syncthreads();
#pragma unroll
    for (int kk = 0; kk < 16; kk++){
      float a[8], g[4], u[4];
      *(float4*)(a)   = *(const float4*)&As[kk][ty*8];
      *(float4*)(a+4) = *(const float4*)&As[kk][ty*8+4];
      *(float4*)(g)   = *(const float4*)&Gs[kk][tx*4];
      *(float4*)(u)   = *(const float4*)&Us[kk][tx*4];
#pragma unroll
      for (int i = 0; i < 8; i++)
#pragma unroll
        for (int j = 0; j < 4; j++){
          accg[i][j] = fmaf(a[i], g[j], accg[i][j]);
          accu[i][j] = fmaf(a[i], u[j], accu[i][j]);
        }
    }
  }
  int n = n0 + tx*4;
#pragma unroll
  for (int i = 0; i < 8; i++){
    int m = m0 + ty*8 + i;
    *(float4*)(C + (size_t)m*N + n) =
        make_float4(siluf(accg[i][0])*accu[i][0], siluf(accg[i][1])*accu[i][1],
                    siluf(accg[i][2])*accu[i][2], siluf(accg[i][3])*accu[i][3]);
  }
}

// ---------------- causal depthwise conv (K=4) + silu over xBC cols ----------------
__global__ __launch_bounds__(256) void conv_silu_k(const float* __restrict__ proj, const float* __restrict__ cw,
                                                   const float* __restrict__ cb, float* __restrict__ out){
  int idx = blockIdx.x*256 + threadIdx.x;
  if (idx >= LMN*CONVD) return;
  int c = idx % CONVD;
  int t = idx / CONVD;
  float acc = cb[c];
#pragma unroll
  for (int kk = 0; kk < KCONV; kk++){
    int ts = t + kk - (KCONV-1);
    if (ts >= 0) acc = fmaf(proj[(size_t)ts*DPROJ + MINTN + c], cw[c*KCONV + kk], acc);
  }
  out[idx] = siluf(acc);
}

__global__ __launch_bounds__(256) void dtprep_k(const float* __restrict__ proj, const float* __restrict__ dtb,
                                                const float* __restrict__ alog, float* __restrict__ dt,
                                                float* __restrict__ dA){
  int idx = blockIdx.x*256 + threadIdx.x;
  if (idx >= LMN*NHEAD) return;
  int h = idx & 15, t = idx >> 4;
  float d = softplusf_(proj[(size_t)t*DPROJ + MINTN + CONVD + h] + dtb[h]);
  dt[idx] = d;
  dA[idx] = expf(-d * expf(alog[h]));
}

// ================= 3-pass chunked SSM scan =================
// Serial depth 1664 -> 128 (pass1, parallel over 13 chunks) + 13 (pass2) + 128 (pass3).
// Block map for passes 1&3: blockIdx = c*64 + h*4 + dgroup; 256 thr = 16 d x 16 nc.
// hloc layout: [c][h][n][d] (n = nc*16+i), i.e. ((c*16+h)*256 + n)*64 + d.

// pass 2 helper: aQ[c][h] = prod of dA over chunk c. 208 blocks x 64 lanes, wave multiply-reduce.
__global__ __launch_bounds__(64) void chunk_prod_k(const float* __restrict__ dAb, float* __restrict__ aQ){
  int c = blockIdx.x >> 4, h = blockIdx.x & 15;
  int lane = threadIdx.x;
  float p = dAb[(c*SCHUNK + lane)*NHEAD + h] * dAb[(c*SCHUNK + 64 + lane)*NHEAD + h];
#pragma unroll
  for (int m = 32; m > 0; m >>= 1) p *= __shfl_xor(p, m);
  if (lane == 0) aQ[c*NHEAD + h] = p;
}

// pass 1: local end-state of each chunk starting from 0 (no y, no C)
__global__ __launch_bounds__(256) void scan_local_k(const float* __restrict__ cv, const float* __restrict__ dtb,
                                                    const float* __restrict__ dAb, float* __restrict__ hloc){
  int c = blockIdx.x >> 6;
  int sub = blockIdx.x & 63;
  int h = sub >> 2;
  int d = (sub & 3)*16 + (threadIdx.x >> 4);
  int nc = threadIdx.x & 15;
  int g = h >> 2;
  const float* xp = cv + h*HEADD + d;
  const float* Bp = cv + MINTN + g*STATEN + nc*16;
  int t0 = c*SCHUNK;
  float s[16];
#pragma unroll
  for (int i = 0; i < 16; i++) s[i] = 0.f;

  float4 B0[4], B1[4];
  float x0, dt0, dA0, x1, dt1, dA1;
  {
    size_t o = (size_t)t0*CONVD;
    x0 = xp[o]; dt0 = dtb[t0*NHEAD + h]; dA0 = dAb[t0*NHEAD + h];
    B0[0]=((const float4*)(Bp+o))[0]; B0[1]=((const float4*)(Bp+o))[1];
    B0[2]=((const float4*)(Bp+o))[2]; B0[3]=((const float4*)(Bp+o))[3];
    o = (size_t)(t0+1)*CONVD;
    x1 = xp[o]; dt1 = dtb[(t0+1)*NHEAD + h]; dA1 = dAb[(t0+1)*NHEAD + h];
    B1[0]=((const float4*)(Bp+o))[0]; B1[1]=((const float4*)(Bp+o))[1];
    B1[2]=((const float4*)(Bp+o))[2]; B1[3]=((const float4*)(Bp+o))[3];
  }
  for (int tt = 0; tt < SCHUNK; tt += 2){
    {
      float coef = dt0 * x0;
      const float* bf = (const float*)B0;
#pragma unroll
      for (int i = 0; i < 16; i++) s[i] = fmaf(s[i], dA0, coef*bf[i]);
      int tn = t0 + ((tt+2 < SCHUNK) ? tt+2 : SCHUNK-1);
      size_t o = (size_t)tn*CONVD;
      x0 = xp[o]; dt0 = dtb[tn*NHEAD + h]; dA0 = dAb[tn*NHEAD + h];
      B0[0]=((const float4*)(Bp+o))[0]; B0[1]=((const float4*)(Bp+o))[1];
      B0[2]=((const float4*)(Bp+o))[2]; B0[3]=((const float4*)(Bp+o))[3];
    }
    {
      float coef = dt1 * x1;
      const float* bf = (const float*)B1;
#pragma unroll
      for (int i = 0; i < 16; i++) s[i] = fmaf(s[i], dA1, coef*bf[i]);
      int tn = t0 + ((tt+3 < SCHUNK) ? tt+3 : SCHUNK-1);
      size_t o = (size_t)tn*CONVD;
      x1 = xp[o]; dt1 = dtb[tn*NHEAD + h]; dA1 = dAb[tn*NHEAD + h];
      B1[0]=((const float4*)(Bp+o))[0]; B1[1]=((const float4*)(Bp+o))[1];
      B1[2]=((const float4*)(Bp+o))[2]; B1[3]=((const float4*)(Bp+o))[3];
    }
  }
  size_t base = ((size_t)(c*NHEAD + h)*STATEN + nc*16)*64 + d;
#pragma unroll
  for (int i = 0; i < 16; i++) hloc[base + (size_t)i*64] = s[i];
}

// pass 2: in-place convert hloc[c] -> entry state H_start[c]
__global__ __launch_bounds__(256) void chunk_combine_k(float* __restrict__ hloc, const float* __restrict__ aQ){
  int e = blockIdx.x*256 + threadIdx.x;      // 16*256*64 = 262144 elements
  int h = e >> 14;
  float s = 0.f;
  for (int c = 0; c < NCHUNK; c++){
    float a = aQ[c*NHEAD + h];
    size_t off = (size_t)c*(NHEAD*STATEN*64) + e;
    float tmp = hloc[off];
    hloc[off] = s;
    s = fmaf(s, a, tmp);
  }
}

// pass 3: full scan within chunk from entry state, emitting y
__global__ __launch_bounds__(256) void scan_out_k(const float* __restrict__ cv, const float* __restrict__ dtb,
                                                  const float* __restrict__ dAb, const float* __restrict__ Dp,
                                                  const float* __restrict__ hstart, float* __restrict__ ys){
  int c = blockIdx.x >> 6;
  int sub = blockIdx.x & 63;
  int h = sub >> 2;
  int d = (sub & 3)*16 + (threadIdx.x >> 4);
  int nc = threadIdx.x & 15;
  int g = h >> 2;
  const float* xp = cv + h*HEADD + d;
  const float* Bp = cv + MINTN + g*STATEN + nc*16;
  const float* Cp = cv + MINTN + 1024 + g*STATEN + nc*16;
  float Dh = Dp[h];
  int t0 = c*SCHUNK;
  float s[16];
  {
    size_t base = ((size_t)(c*NHEAD + h)*STATEN + nc*16)*64 + d;
#pragma unroll
    for (int i = 0; i < 16; i++) s[i] = hstart[base + (size_t)i*64];
  }

  float4 B0[4], C0[4], B1[4], C1[4];
  float x0, dt0, dA0, x1, dt1, dA1;
  {
    size_t o = (size_t)t0*CONVD;
    x0 = xp[o]; dt0 = dtb[t0*NHEAD + h]; dA0 = dAb[t0*NHEAD + h];
    B0[0]=((const float4*)(Bp+o))[0]; B0[1]=((const float4*)(Bp+o))[1];
    B0[2]=((const float4*)(Bp+o))[2]; B0[3]=((const float4*)(Bp+o))[3];
    C0[0]=((const float4*)(Cp+o))[0]; C0[1]=((const float4*)(Cp+o))[1];
    C0[2]=((const float4*)(Cp+o))[2]; C0[3]=((const float4*)(Cp+o))[3];
    o = (size_t)(t0+1)*CONVD;
    x1 = xp[o]; dt1 = dtb[(t0+1)*NHEAD + h]; dA1 = dAb[(t0+1)*NHEAD + h];
    B1[0]=((const float4*)(Bp+o))[0]; B1[1]=((const float4*)(Bp+o))[1];
    B1[2]=((const float4*)(Bp+o))[2]; B1[3]=((const float4*)(Bp+o))[3];
    C1[0]=((const float4*)(Cp+o))[0]; C1[1]=((const float4*)(Cp+o))[1];
    C1[2]=((const float4*)(Cp+o))[2]; C1[3]=((const float4*)(Cp+o))[3];
  }
  for (int tt = 0; tt < SCHUNK; tt += 2){
    {
      int t = t0 + tt;
      float coef = dt0 * x0;
      float accp[4] = {0.f,0.f,0.f,0.f};
      const float* bf = (const float*)B0;
      const float* cf = (const float*)C0;
#pragma unroll
      for (int i = 0; i < 16; i++){
        s[i] = fmaf(s[i], dA0, coef*bf[i]);
        accp[i & 3] = fmaf(s[i], cf[i], accp[i & 3]);
      }
      float accv = (accp[0]+accp[1])+(accp[2]+accp[3]);
      accv += __shfl_xor(accv, 1); accv += __shfl_xor(accv, 2);
      accv += __shfl_xor(accv, 4); accv += __shfl_xor(accv, 8);
      if (nc == 0) ys[(size_t)t*MINTN + h*HEADD + d] = accv + Dh*x0;
      int tn = t0 + ((tt+2 < SCHUNK) ? tt+2 : SCHUNK-1);
      size_t o = (size_t)tn*CONVD;
      x0 = xp[o]; dt0 = dtb[tn*NHEAD + h]; dA0 = dAb[tn*NHEAD + h];
      B0[0]=((const float4*)(Bp+o))[0]; B0[1]=((const float4*)(Bp+o))[1];
      B0[2]=((const float4*)(Bp+o))[2]; B0[3]=((const float4*)(Bp+o))[3];
      C0[0]=((const float4*)(Cp+o))[0]; C0[1]=((const float4*)(Cp+o))[1];
      C0[2]=((const float4*)(Cp+o))[2]; C0[3]=((const float4*)(Cp+o))[3];
    }
    {
      int t = t0 + tt + 1;
      float coef = dt1 * x1;
      float accp[4] = {0.f,0.f,0.f,0.f};
      const float* bf = (const float*)B1;
      const float* cf = (const float*)C1;
#pragma unroll
      for (int i = 0; i < 16; i++){
        s[i] = fmaf(s[i], dA1, coef*bf[i]);
        accp[i & 3] = fmaf(s[i], cf[i], accp[i & 3]);
      }
      float accv = (accp[0]+accp[1])+(accp[2]+accp[3]);
      accv += __shfl_xor(accv, 1); accv += __shfl_xor(accv, 2);
      accv += __shfl_xor(accv, 4); accv += __shfl_xor(accv, 8);
      if (nc == 0) ys[(size_t)t*MINTN + h*HEADD + d] = accv + Dh*x1;
      int tn = t0 + ((tt+3 < SCHUNK) ? tt+3 : SCHUNK-1);
      size_t o = (size_t)tn*CONVD;
      x1 = xp[o]; dt1 = dtb[tn*NHEAD + h]; dA1 = dAb[tn*NHEAD + h];
      B1[0]=((const float4*)(Bp+o))[0]; B1[1]=((const float4*)(Bp+o))[1];
      B1[2]=((const float4*)(Bp+o))[2]; B1[3]=((const float4*)(Bp+o))[3];
      C1[0]=((const float4*)(Cp+o))[0]; C1[1]=((const float4*)(Cp+o))[1];
      C1[2]=((const float4*)(Cp+o))[2]; C1[3]=((const float4*)(Cp+o))[3];
    }
  }
}

// ---------------- small assembly kernels ----------------
__global__ __launch_bounds__(256) void build_hc_k(const float* __restrict__ hn, const float* __restrict__ memo,
                                                  float* __restrict__ hc){
  int idx = blockIdx.x*256 + threadIdx.x;
  if (idx >= TCN*HDIM) return;
  int r = idx >> 10, c = idx & 1023;
  float v;
  if (r < SINKN)        v = hn[(size_t)r*HDIM + c];
  else if (r == SINKN)  v = memo[(size_t)(LMN-1)*HDIM + c];
  else                  v = hn[(size_t)(r + 1663)*HDIM + c];
  hc[idx] = v;
}

__global__ __launch_bounds__(256) void rope_k(float* __restrict__ q, float* __restrict__ k,
                                              const float* __restrict__ cosp, const float* __restrict__ sinp){
  int idx = blockIdx.x*256 + threadIdx.x;
  if (idx >= TCN*20*32) return;
  int dd = idx & 31;
  int hh = (idx >> 5) % 20;
  int t  = idx / (20*32);
  int ci = (t <= SINKN) ? t : t + 1663;
  float* p = (hh < NHEAD) ? (q + (size_t)t*HDIM + hh*HEADD)
                          : (k + (size_t)t*(NKVH*HEADD) + (hh - NHEAD)*HEADD);
  float a = p[dd], b = p[dd+32];
  float c0 = cosp[(size_t)ci*HEADD + dd], c1 = cosp[(size_t)ci*HEADD + dd + 32];
  float s0 = sinp[(size_t)ci*HEADD + dd], s1 = sinp[(size_t)ci*HEADD + dd + 32];
  p[dd]    = a*c0 - b*s0;
  p[dd+32] = b*c1 + a*s1;
}

// ---------------- flash-style fp32 attention, Tc=385, causal, GQA 16q/4kv ----------------
__global__ __launch_bounds__(256) void attn_k(const float* __restrict__ q, const float* __restrict__ k,
                                              const float* __restrict__ v, float* __restrict__ aoc){
  __shared__ float Qs[64][65];   // Q tile; reused as P tile after hoist
  __shared__ float Ks[64][65];
  __shared__ float Vs[64][68];
  int qt = blockIdx.x, h = blockIdx.y;
  int tid = threadIdx.x;
  int ql = tid >> 2, dg = tid & 3;
  int qg = qt*64 + ql;
  int kvh = h >> 2;
#pragma unroll
  for (int i = 0; i < 16; i++){
    int idx = tid + 256*i;
    int r = idx >> 6, c = idx & 63;
    int qr = qt*64 + r;
    Qs[r][c] = (qr < TCN) ? q[(size_t)qr*HDIM + h*HEADD + c] : 0.f;
  }
  __syncthreads();
  float qreg[64];
#pragma unroll
  for (int d2 = 0; d2 < 64; d2++) qreg[d2] = Qs[ql][d2];
  __syncthreads();  // Qs is reused as P storage below

  float mrun = -INFINITY, lrun = 0.f;
  float acc[16];
#pragma unroll
  for (int i = 0; i < 16; i++) acc[i] = 0.f;

  for (int kt = 0; kt <= qt; kt++){
    __syncthreads();
#pragma unroll
    for (int i = 0; i < 16; i++){
      int idx = tid + 256*i;
      int r = idx >> 6, c = idx & 63;
      int kr = kt*64 + r;
      float kv = 0.f, vv = 0.f;
      if (kr < TCN){
        kv = k[(size_t)kr*(NKVH*HEADD) + kvh*HEADD + c];
        vv = v[(size_t)kr*(NKVH*HEADD) + kvh*HEADD + c];
      }
      Ks[r][c] = kv; Vs[r][c] = vv;
    }
    __syncthreads();
    float p[16]; float tmax = -INFINITY;
#pragma unroll
    for (int jj = 0; jj < 16; jj++){
      int j = jj*4 + dg;            // key-interleave keeps LDS banks conflict-free
      float sv = 0.f;
#pragma unroll
      for (int d2 = 0; d2 < 64; d2++) sv = fmaf(qreg[d2], Ks[j][d2], sv);
      sv *= 0.125f;                  // HD^-0.5
      int kr = kt*64 + j;
      if (kr > qg || kr >= TCN) sv = -INFINITY;
      p[jj] = sv;
      tmax = fmaxf(tmax, sv);
    }
    tmax = fmaxf(tmax, __shfl_xor(tmax, 1));
    tmax = fmaxf(tmax, __shfl_xor(tmax, 2));
    float nm = fmaxf(mrun, tmax);
    if (nm == -INFINITY) nm = 0.f;  // fully-masked rows: avoid NaN
    float sc = expf(mrun - nm);
    float sump = 0.f;
#pragma unroll
    for (int jj = 0; jj < 16; jj++){ p[jj] = expf(p[jj] - nm); sump += p[jj]; }
    sump += __shfl_xor(sump, 1);
    sump += __shfl_xor(sump, 2);
    lrun = lrun*sc + sump;
    mrun = nm;
#pragma unroll
    for (int i = 0; i < 16; i++) acc[i] *= sc;
#pragma unroll
    for (int jj = 0; jj < 16; jj++) Qs[ql][jj*4 + dg] = p[jj];
    __syncthreads();
#pragma unroll
    for (int j = 0; j < 64; j++){
      float pv = Qs[ql][j];
#pragma unroll
      for (int c4 = 0; c4 < 4; c4++){
        float4 vv = *(const float4*)&Vs[j][dg*16 + c4*4];
        acc[c4*4+0] = fmaf(pv, vv.x, acc[c4*4+0]);
        acc[c4*4+1] = fmaf(pv, vv.y, acc[c4*4+1]);
        acc[c4*4+2] = fmaf(pv, vv.z, acc[c4*4+2]);
        acc[c4*4+3] = fmaf(pv, vv.w, acc[c4*4+3]);
      }
    }
  }
  if (qg < TCN){
    float inv = 1.0f / lrun;
#pragma unroll
    for (int c4 = 0; c4 < 4; c4++){
      *(float4*)(aoc + (size_t)qg*HDIM + h*HEADD + dg*16 + c4*4) =
          make_float4(acc[c4*4]*inv, acc[c4*4+1]*inv, acc[c4*4+2]*inv, acc[c4*4+3]*inv);
    }
  }
}

__global__ __launch_bounds__(256) void build_ao_k(const float* __restrict__ aoc, const float* __restrict__ memo,
                                                  float* __restrict__ aof){
  int idx = blockIdx.x*256 + threadIdx.x;
  if (idx >= TLEN*HDIM) return;
  int r = idx >> 10, c = idx & 1023;
  float v;
  if (r < SINKN)              v = aoc[(size_t)r*HDIM + c];
  else if (r < TLEN - WINN)   v = memo[(size_t)(r - SINKN)*HDIM + c];
  else                        v = aoc[(size_t)(r - 1663)*HDIM + c];
  aof[idx] = v;
}

extern "C" void kernel_launch(void* const* d_in, const int* in_sizes, int n_in,
                              void* d_out, int out_size, void* d_ws, size_t ws_size,
                              hipStream_t stream){
  (void)in_sizes; (void)n_in; (void)out_size; (void)ws_size;
  const float* x      = (const float*)d_in[0];
  const float* cosp   = (const float*)d_in[1];
  const float* sinp   = (const float*)d_in[2];
  const float* ln1_w  = (const float*)d_in[3];
  const float* q_w    = (const float*)d_in[4];
  const float* q_b    = (const float*)d_in[5];
  const float* k_w    = (const float*)d_in[6];
  const float* k_b    = (const float*)d_in[7];
  const float* v_w    = (const float*)d_in[8];
  const float* v_b    = (const float*)d_in[9];
  const float* o_w    = (const float*)d_in[10];
  const float* inpw   = (const float*)d_in[11];
  const float* convw  = (const float*)d_in[12];
  const float* convb  = (const float*)d_in[13];
  const float* dtbias = (const float*)d_in[14];
  const float* alog   = (const float*)d_in[15];
  const float* Dp     = (const float*)d_in[16];
  const float* mnw    = (const float*)d_in[17];
  const float* moutw  = (const float*)d_in[18];
  const float* ln2_w  = (const float*)d_in[19];
  const float* gatew  = (const float*)d_in[20];
  const float* upw    = (const float*)d_in[21];
  const float* downw  = (const float*)d_in[22];
  float* out = (float*)d_out;

  // Workspace overlay (floats). Peak = 19,216,592 floats = 73.3 MiB.
  float* w     = (float*)d_ws;
  float* hn    = w + 0;
  float* proj  = w + 2097152;
  float* conv  = w + 8939520;
  float* memo  = w + 8939520;
  float* mamx  = w + 10643456;
  float* dtb   = w + 14051328;
  float* dAb   = w + 14077952;
  float* yscan = w + 14104576;
  float* hc    = w + 14104576;
  float* qb    = w + 14498816;
  float* kb    = w + 14893056;
  float* vb    = w + 14991616;
  float* aoc   = w + 15090176;
  float* hloc  = w + 15808512;
  float* aQ    = w + 19216384;
  float* aof   = w + 2097152;
  float* h1    = w + 0;
  float* mlpin = w + 2097152;
  float* gu    = w + 4194304;

  // 1. ln1
  rmsnorm_k<<<TLEN, 256, 0, stream>>>(x, ln1_w, hn);
  // 2. mamba in_proj on evicted rows [128,1792)
  gemm_k<0><<<dim3(65, 13), 256, 0, stream>>>(hn + (size_t)SINKN*HDIM, inpw, proj, nullptr, nullptr, LMN, DPROJ, HDIM);
  // 3. conv + silu
  conv_silu_k<<<(LMN*CONVD + 255)/256, 256, 0, stream>>>(proj, convw, convb, conv);
  // 4. dt = softplus(dt+bias), dA = exp(dt*A)
  dtprep_k<<<(LMN*NHEAD + 255)/256, 256, 0, stream>>>(proj, dtbias, alog, dtb, dAb);
  // 5. chunked scan: chunk decay -> local states -> combine -> outputs
  chunk_prod_k<<<NCHUNK*NHEAD, 64, 0, stream>>>(dAb, aQ);
  scan_local_k<<<NCHUNK*64, 256, 0, stream>>>(conv, dtb, dAb, hloc);
  chunk_combine_k<<<1024, 256, 0, stream>>>(hloc, aQ);
  scan_out_k<<<NCHUNK*64, 256, 0, stream>>>(conv, dtb, dAb, Dp, hloc, yscan);
  // 6. gate by silu(z), rmsnorm
  gated_rmsnorm_k<<<LMN, 256, 0, stream>>>(yscan, proj, mnw, mamx);
  // 7. mamba out proj (64-tile: 16x26 = 416 blocks)
  gemm64_k<0><<<dim3(16, 26), 256, 0, stream>>>(mamx, moutw, memo, nullptr, nullptr, LMN, HDIM, HDIM);
  // 8. compressed sequence hc (385 tokens)
  build_hc_k<<<(TCN*HDIM + 255)/256, 256, 0, stream>>>(hn, memo, hc);
  // 9-11. qkv projections (+bias), 64-tile
  gemm64_k<1><<<dim3(16, 7), 256, 0, stream>>>(hc, q_w, qb, q_b, nullptr, TCN, HDIM, HDIM);
  gemm64_k<1><<<dim3(4, 7), 256, 0, stream>>>(hc, k_w, kb, k_b, nullptr, TCN, NKVH*HEADD, HDIM);
  gemm64_k<1><<<dim3(4, 7), 256, 0, stream>>>(hc, v_w, vb, v_b, nullptr, TCN, NKVH*HEADD, HDIM);
  // 12. rope on q,k (concatenated cos/sin indexing)
  rope_k<<<(TCN*20*32 + 255)/256, 256, 0, stream>>>(qb, kb, cosp, sinp);
  // 13. causal attention
  attn_k<<<dim3(7, 16), 256, 0, stream>>>(qb, kb, vb, aoc);
  // 14. splice mem_out back into full-length ao
  build_ao_k<<<(TLEN*HDIM + 255)/256, 256, 0, stream>>>(aoc, memo, aof);
  // 15. o_proj + residual x -> h1 (64-tile: 16x32 = 512 blocks, 2/CU)
  gemm64_k<2><<<dim3(16, 32), 256, 0, stream>>>(aof, o_w, h1, nullptr, x, TLEN, HDIM, HDIM);
  // 16. ln2
  rmsnorm_k<<<TLEN, 256, 0, stream>>>(h1, ln2_w, mlpin);
  // 17. fused gate/up proj: gu = silu(mlpin@gate_w) * (mlpin@up_w)
  gemm_gateup_k<<<dim3(64, 16), 256, 0, stream>>>(mlpin, gatew, upw, gu, TLEN, INTERN, HDIM);
  // 18. down proj + residual h1 -> out (64-tile: 16x32 = 512 blocks, 2/CU)
  gemm64_k<2><<<dim3(16, 32), 256, 0, stream>>>(gu, downw, out, nullptr, h1, TLEN, HDIM, INTERN);
}

// Round 9
// 1752.425 us; speedup vs baseline: 2.2390x; 1.1445x over previous
//
#include <hip/hip_runtime.h>
#include <hip/hip_bf16.h>
#include <math.h>

#define TLEN 2048
#define HDIM 1024
#define NHEAD 16
#define HEADD 64
#define NKVH 4
#define SINKN 128
#define WINN 256
#define STATEN 256
#define KCONV 4
#define MINTN 1024
#define CONVD 3072
#define DPROJ 4112
#define INTERN 4096
#define LMN 1664
#define TCN 385
#define EPSF 1e-6f
#define SCHUNK 128
#define NCHUNK 13   /* 13*128 = 1664 */

typedef __attribute__((ext_vector_type(8))) short bf16x8;
typedef __attribute__((ext_vector_type(4))) float f32x4;

__device__ __forceinline__ float siluf(float x){ return x / (1.0f + expf(-x)); }
__device__ __forceinline__ float softplusf_(float x){ return fmaxf(x, 0.0f) + log1pf(expf(-fabsf(x))); }
__device__ __forceinline__ unsigned short bftr(float x){ return (unsigned short)(__float_as_uint(x) >> 16); }
__device__ __forceinline__ float bfval(unsigned short h){ return __uint_as_float(((unsigned int)h) << 16); }

__device__ __forceinline__ float block_sum256(float v, float* sb){
#pragma unroll
  for (int m = 32; m > 0; m >>= 1) v += __shfl_xor(v, m);
  int wid = threadIdx.x >> 6;
  if ((threadIdx.x & 63) == 0) sb[wid] = v;
  __syncthreads();
  return sb[0] + sb[1] + sb[2] + sb[3];
}

// ---------------- rmsnorm ----------------
__global__ __launch_bounds__(256) void rmsnorm_k(const float* __restrict__ in, const float* __restrict__ w,
                                                 float* __restrict__ out){
  __shared__ float sb[4];
  size_t r = blockIdx.x;
  float4 x = ((const float4*)(in + r*HDIM))[threadIdx.x];
  float ss = block_sum256(x.x*x.x + x.y*x.y + x.z*x.z + x.w*x.w, sb);
  float sc = 1.0f / sqrtf(ss*(1.0f/HDIM) + EPSF);
  float4 wv = ((const float4*)w)[threadIdx.x];
  ((float4*)(out + r*HDIM))[threadIdx.x] =
      make_float4(x.x*sc*wv.x, x.y*sc*wv.y, x.z*sc*wv.z, x.w*sc*wv.w);
}

__global__ __launch_bounds__(256) void gated_rmsnorm_k(const float* __restrict__ ys, const float* __restrict__ proj,
                                                       const float* __restrict__ w, float* __restrict__ out){
  __shared__ float sb[4];
  size_t r = blockIdx.x;
  float4 y = ((const float4*)(ys + r*MINTN))[threadIdx.x];
  float4 z = ((const float4*)(proj + r*DPROJ))[threadIdx.x];
  y.x *= siluf(z.x); y.y *= siluf(z.y); y.z *= siluf(z.z); y.w *= siluf(z.w);
  float ss = block_sum256(y.x*y.x + y.y*y.y + y.z*y.z + y.w*y.w, sb);
  float sc = 1.0f / sqrtf(ss*(1.0f/MINTN) + EPSF);
  float4 wv = ((const float4*)w)[threadIdx.x];
  ((float4*)(out + r*MINTN))[threadIdx.x] =
      make_float4(y.x*sc*wv.x, y.y*sc*wv.y, y.z*sc*wv.z, y.w*sc*wv.w);
}

// ================= split-bf16 MFMA GEMM =================
// C[M,N] = A[M,K]@B[K,N] in ~fp32 precision via Ah+Al / Bh+Bl bf16 pairs,
// acc += Al*Bh + Ah*Bl + Ah*Bh (lo*lo ~2^-16 dropped).
// BM=BN=128 BK=32, 256 thr = 4 waves (2x2), each wave 64x64 = 4x4 frags of
// v_mfma_f32_16x16x32_bf16. M,K must be multiples of 128/32 (true for all
// callers); N arbitrary multiple of 4 (guarded; in_proj N=4112).
// EPI: 0 none, 2 +=extra[m,n], 3 *=silu(extra[m,n]) (extra may alias C).
template<int EPI>
__global__ __launch_bounds__(256) void mfma_gemm_k(const float* __restrict__ A, const float* __restrict__ B,
                                                   float* C, const float* extra,
                                                   int M, int N, int K){
  __shared__ unsigned short Ah[128*40], Al[128*40], Bh[128*40], Bl[128*40]; // pad 32->40 (2-way banks)
  int tid = threadIdx.x;
  int lane = tid & 63, wid = tid >> 6;
  int wr = (wid >> 1) * 64, wc = (wid & 1) * 64;
  int lr = lane & 15, kg = lane >> 4;
  int m0 = blockIdx.y * 128, n0 = blockIdx.x * 128;

  int arow = tid >> 1, akc = (tid & 1) * 16;  // A staging: 2 thr/row, 16 k each
  int bp = tid >> 4;                          // B staging: k-pair 2bp,2bp+1
  int ba = tid & 15;                          // 8-col sub-block

  f32x4 acc[4][4];
#pragma unroll
  for (int i = 0; i < 4; i++)
#pragma unroll
    for (int j = 0; j < 4; j++) acc[i][j] = (f32x4){0.f, 0.f, 0.f, 0.f};

  for (int k0 = 0; k0 < K; k0 += 32){
    // ---- global loads into registers (constant-indexed; stays in VGPRs) ----
    const float* ap = A + (size_t)(m0 + arow)*K + k0 + akc;
    float4 av0 = *(const float4*)(ap);
    float4 av1 = *(const float4*)(ap + 4);
    float4 av2 = *(const float4*)(ap + 8);
    float4 av3 = *(const float4*)(ap + 12);
    const float* b0p = B + (size_t)(k0 + 2*bp)*N + n0;
    const float* b1p = b0p + N;
    float xb0[8], xb1[8];
#pragma unroll
    for (int j = 0; j < 8; j++){
      int b = (j + ba) & 7;            // col-stagger: concurrent LDS writes 2-way max
      int col = ba*8 + b;
      bool ok = (n0 + col) < N;
      xb0[j] = ok ? b0p[col] : 0.f;
      xb1[j] = ok ? b1p[col] : 0.f;
    }
    __syncthreads();   // prior iteration's frag reads complete
    // ---- A: split + write [row][k] ----
    {
      float va[16] = {av0.x,av0.y,av0.z,av0.w, av1.x,av1.y,av1.z,av1.w,
                      av2.x,av2.y,av2.z,av2.w, av3.x,av3.y,av3.z,av3.w};
      bf16x8 vh0, vh1, vl0, vl1;
#pragma unroll
      for (int e = 0; e < 8; e++){
        unsigned short h0 = bftr(va[e]);     vh0[e] = (short)h0;
        vl0[e] = (short)bftr(va[e] - bfval(h0));
        unsigned short h1 = bftr(va[e+8]);   vh1[e] = (short)h1;
        vl1[e] = (short)bftr(va[e+8] - bfval(h1));
      }
      int ai = arow*40 + akc;
      *(bf16x8*)&Ah[ai] = vh0; *(bf16x8*)&Ah[ai+8] = vh1;
      *(bf16x8*)&Al[ai] = vl0; *(bf16x8*)&Al[ai+8] = vl1;
    }
    // ---- B: split + transposed write [col][k] (b32 packs k-pair) ----
#pragma unroll
    for (int j = 0; j < 8; j++){
      int b = (j + ba) & 7;
      int col = ba*8 + b;
      unsigned short h0 = bftr(xb0[j]), h1 = bftr(xb1[j]);
      unsigned int hh = (unsigned int)h0 | ((unsigned int)h1 << 16);
      unsigned short l0 = bftr(xb0[j] - bfval(h0)), l1 = bftr(xb1[j] - bfval(h1));
      unsigned int ll = (unsigned int)l0 | ((unsigned int)l1 << 16);
      *(unsigned int*)&Bh[col*40 + 2*bp] = hh;
      *(unsigned int*)&Bl[col*40 + 2*bp] = ll;
    }
    __syncthreads();
    // ---- fragments + MFMA ----
    bf16x8 fah[4], fal[4], fbh[4], fbl[4];
#pragma unroll
    for (int f = 0; f < 4; f++){
      int ai = (wr + f*16 + lr)*40 + kg*8;
      fah[f] = *(const bf16x8*)&Ah[ai];
      fal[f] = *(const bf16x8*)&Al[ai];
      int bi = (wc + f*16 + lr)*40 + kg*8;
      fbh[f] = *(const bf16x8*)&Bh[bi];
      fbl[f] = *(const bf16x8*)&Bl[bi];
    }
#pragma unroll
    for (int fr = 0; fr < 4; fr++)
#pragma unroll
      for (int fc = 0; fc < 4; fc++){
        acc[fr][fc] = __builtin_amdgcn_mfma_f32_16x16x32_bf16(fal[fr], fbh[fc], acc[fr][fc], 0, 0, 0);
        acc[fr][fc] = __builtin_amdgcn_mfma_f32_16x16x32_bf16(fah[fr], fbl[fc], acc[fr][fc], 0, 0, 0);
        acc[fr][fc] = __builtin_amdgcn_mfma_f32_16x16x32_bf16(fah[fr], fbh[fc], acc[fr][fc], 0, 0, 0);
      }
  }
  // ---- epilogue: C/D layout col=lane&15, row=(lane>>4)*4+j (m89-verified) ----
#pragma unroll
  for (int fr = 0; fr < 4; fr++)
#pragma unroll
    for (int fc = 0; fc < 4; fc++)
#pragma unroll
      for (int j = 0; j < 4; j++){
        int row = m0 + wr + fr*16 + kg*4 + j;
        int col = n0 + wc + fc*16 + lr;
        if (col < N){
          float r = acc[fr][fc][j];
          if (EPI == 2) r += extra[(size_t)row*N + col];
          if (EPI == 3) r *= siluf(extra[(size_t)row*N + col]);
          C[(size_t)row*N + col] = r;
        }
      }
}

// ---------------- fp32 GEMM, 64x64 tile (qkv only: M=385) ----------------
template<int EPI>
__global__ __launch_bounds__(256) void gemm64_k(const float* __restrict__ A, const float* __restrict__ B,
                                                float* __restrict__ C, const float* __restrict__ bias,
                                                const float* __restrict__ extra, int M, int N, int K){
  __shared__ float As[16][68];
  __shared__ float Bs[16][64];
  int tid = threadIdx.x;
  int tx = tid & 15, ty = tid >> 4;
  int m0 = blockIdx.y * 64, n0 = blockIdx.x * 64;
  int ar = tid >> 2, ak = (tid & 3) * 4;
  int bk = tid >> 4, bn = (tid & 15) * 4;
  float acc[4][4];
#pragma unroll
  for (int i = 0; i < 4; i++)
#pragma unroll
    for (int j = 0; j < 4; j++) acc[i][j] = 0.f;

  for (int k0 = 0; k0 < K; k0 += 16){
    float4 a0 = make_float4(0,0,0,0);
    if (m0 + ar < M) a0 = *(const float4*)(A + (size_t)(m0+ar)*K + k0 + ak);
    float4 b0 = *(const float4*)(B + (size_t)(k0+bk)*N + n0 + bn);
    __syncthreads();
    As[ak+0][ar] = a0.x; As[ak+1][ar] = a0.y; As[ak+2][ar] = a0.z; As[ak+3][ar] = a0.w;
    *(float4*)&Bs[bk][bn] = b0;
    __syncthreads();
#pragma unroll
    for (int kk = 0; kk < 16; kk++){
      float a[4], b[4];
      *(float4*)(a) = *(const float4*)&As[kk][ty*4];
      *(float4*)(b) = *(const float4*)&Bs[kk][tx*4];
#pragma unroll
      for (int i = 0; i < 4; i++)
#pragma unroll
        for (int j = 0; j < 4; j++) acc[i][j] = fmaf(a[i], b[j], acc[i][j]);
    }
  }
  int n = n0 + tx*4;
#pragma unroll
  for (int i = 0; i < 4; i++){
    int m = m0 + ty*4 + i;
    if (m >= M) break;
    float r0 = acc[i][0], r1 = acc[i][1], r2 = acc[i][2], r3 = acc[i][3];
    if (EPI == 1){ r0 += bias[n]; r1 += bias[n+1]; r2 += bias[n+2]; r3 += bias[n+3]; }
    if (EPI == 2){ const float* e = extra + (size_t)m*N + n; r0 += e[0]; r1 += e[1]; r2 += e[2]; r3 += e[3]; }
    *(float4*)(C + (size_t)m*N + n) = make_float4(r0, r1, r2, r3);
  }
}

// ---------------- conv + silu ----------------
__global__ __launch_bounds__(256) void conv_silu_k(const float* __restrict__ proj, const float* __restrict__ cw,
                                                   const float* __restrict__ cb, float* __restrict__ out){
  int idx = blockIdx.x*256 + threadIdx.x;
  if (idx >= LMN*CONVD) return;
  int c = idx % CONVD;
  int t = idx / CONVD;
  float acc = cb[c];
#pragma unroll
  for (int kk = 0; kk < KCONV; kk++){
    int ts = t + kk - (KCONV-1);
    if (ts >= 0) acc = fmaf(proj[(size_t)ts*DPROJ + MINTN + c], cw[c*KCONV + kk], acc);
  }
  out[idx] = siluf(acc);
}

__global__ __launch_bounds__(256) void dtprep_k(const float* __restrict__ proj, const float* __restrict__ dtb,
                                                const float* __restrict__ alog, float* __restrict__ dt,
                                                float* __restrict__ dA){
  int idx = blockIdx.x*256 + threadIdx.x;
  if (idx >= LMN*NHEAD) return;
  int h = idx & 15, t = idx >> 4;
  float d = softplusf_(proj[(size_t)t*DPROJ + MINTN + CONVD + h] + dtb[h]);
  dt[idx] = d;
  dA[idx] = expf(-d * expf(alog[h]));
}

// ================= 3-pass chunked SSM scan =================
__global__ __launch_bounds__(64) void chunk_prod_k(const float* __restrict__ dAb, float* __restrict__ aQ){
  int c = blockIdx.x >> 4, h = blockIdx.x & 15;
  int lane = threadIdx.x;
  float p = dAb[(c*SCHUNK + lane)*NHEAD + h] * dAb[(c*SCHUNK + 64 + lane)*NHEAD + h];
#pragma unroll
  for (int m = 32; m > 0; m >>= 1) p *= __shfl_xor(p, m);
  if (lane == 0) aQ[c*NHEAD + h] = p;
}

__global__ __launch_bounds__(256) void scan_local_k(const float* __restrict__ cv, const float* __restrict__ dtb,
                                                    const float* __restrict__ dAb, float* __restrict__ hloc){
  int c = blockIdx.x >> 6;
  int sub = blockIdx.x & 63;
  int h = sub >> 2;
  int d = (sub & 3)*16 + (threadIdx.x >> 4);
  int nc = threadIdx.x & 15;
  int g = h >> 2;
  const float* xp = cv + h*HEADD + d;
  const float* Bp = cv + MINTN + g*STATEN + nc*16;
  int t0 = c*SCHUNK;
  float s[16];
#pragma unroll
  for (int i = 0; i < 16; i++) s[i] = 0.f;

  float4 B0[4], B1[4];
  float x0, dt0, dA0, x1, dt1, dA1;
  {
    size_t o = (size_t)t0*CONVD;
    x0 = xp[o]; dt0 = dtb[t0*NHEAD + h]; dA0 = dAb[t0*NHEAD + h];
    B0[0]=((const float4*)(Bp+o))[0]; B0[1]=((const float4*)(Bp+o))[1];
    B0[2]=((const float4*)(Bp+o))[2]; B0[3]=((const float4*)(Bp+o))[3];
    o = (size_t)(t0+1)*CONVD;
    x1 = xp[o]; dt1 = dtb[(t0+1)*NHEAD + h]; dA1 = dAb[(t0+1)*NHEAD + h];
    B1[0]=((const float4*)(Bp+o))[0]; B1[1]=((const float4*)(Bp+o))[1];
    B1[2]=((const float4*)(Bp+o))[2]; B1[3]=((const float4*)(Bp+o))[3];
  }
  for (int tt = 0; tt < SCHUNK; tt += 2){
    {
      float coef = dt0 * x0;
      const float* bf = (const float*)B0;
#pragma unroll
      for (int i = 0; i < 16; i++) s[i] = fmaf(s[i], dA0, coef*bf[i]);
      int tn = t0 + ((tt+2 < SCHUNK) ? tt+2 : SCHUNK-1);
      size_t o = (size_t)tn*CONVD;
      x0 = xp[o]; dt0 = dtb[tn*NHEAD + h]; dA0 = dAb[tn*NHEAD + h];
      B0[0]=((const float4*)(Bp+o))[0]; B0[1]=((const float4*)(Bp+o))[1];
      B0[2]=((const float4*)(Bp+o))[2]; B0[3]=((const float4*)(Bp+o))[3];
    }
    {
      float coef = dt1 * x1;
      const float* bf = (const float*)B1;
#pragma unroll
      for (int i = 0; i < 16; i++) s[i] = fmaf(s[i], dA1, coef*bf[i]);
      int tn = t0 + ((tt+3 < SCHUNK) ? tt+3 : SCHUNK-1);
      size_t o = (size_t)tn*CONVD;
      x1 = xp[o]; dt1 = dtb[tn*NHEAD + h]; dA1 = dAb[tn*NHEAD + h];
      B1[0]=((const float4*)(Bp+o))[0]; B1[1]=((const float4*)(Bp+o))[1];
      B1[2]=((const float4*)(Bp+o))[2]; B1[3]=((const float4*)(Bp+o))[3];
    }
  }
  size_t base = ((size_t)(c*NHEAD + h)*STATEN + nc*16)*64 + d;
#pragma unroll
  for (int i = 0; i < 16; i++) hloc[base + (size_t)i*64] = s[i];
}

__global__ __launch_bounds__(256) void chunk_combine_k(float* __restrict__ hloc, const float* __restrict__ aQ){
  int e = blockIdx.x*256 + threadIdx.x;
  int h = e >> 14;
  float s = 0.f;
  for (int c = 0; c < NCHUNK; c++){
    float a = aQ[c*NHEAD + h];
    size_t off = (size_t)c*(NHEAD*STATEN*64) + e;
    float tmp = hloc[off];
    hloc[off] = s;
    s = fmaf(s, a, tmp);
  }
}

__global__ __launch_bounds__(256) void scan_out_k(const float* __restrict__ cv, const float* __restrict__ dtb,
                                                  const float* __restrict__ dAb, const float* __restrict__ Dp,
                                                  const float* __restrict__ hstart, float* __restrict__ ys){
  int c = blockIdx.x >> 6;
  int sub = blockIdx.x & 63;
  int h = sub >> 2;
  int d = (sub & 3)*16 + (threadIdx.x >> 4);
  int nc = threadIdx.x & 15;
  int g = h >> 2;
  const float* xp = cv + h*HEADD + d;
  const float* Bp = cv + MINTN + g*STATEN + nc*16;
  const float* Cp = cv + MINTN + 1024 + g*STATEN + nc*16;
  float Dh = Dp[h];
  int t0 = c*SCHUNK;
  float s[16];
  {
    size_t base = ((size_t)(c*NHEAD + h)*STATEN + nc*16)*64 + d;
#pragma unroll
    for (int i = 0; i < 16; i++) s[i] = hstart[base + (size_t)i*64];
  }

  float4 B0[4], C0[4], B1[4], C1[4];
  float x0, dt0, dA0, x1, dt1, dA1;
  {
    size_t o = (size_t)t0*CONVD;
    x0 = xp[o]; dt0 = dtb[t0*NHEAD + h]; dA0 = dAb[t0*NHEAD + h];
    B0[0]=((const float4*)(Bp+o))[0]; B0[1]=((const float4*)(Bp+o))[1];
    B0[2]=((const float4*)(Bp+o))[2]; B0[3]=((const float4*)(Bp+o))[3];
    C0[0]=((const float4*)(Cp+o))[0]; C0[1]=((const float4*)(Cp+o))[1];
    C0[2]=((const float4*)(Cp+o))[2]; C0[3]=((const float4*)(Cp+o))[3];
    o = (size_t)(t0+1)*CONVD;
    x1 = xp[o]; dt1 = dtb[(t0+1)*NHEAD + h]; dA1 = dAb[(t0+1)*NHEAD + h];
    B1[0]=((const float4*)(Bp+o))[0]; B1[1]=((const float4*)(Bp+o))[1];
    B1[2]=((const float4*)(Bp+o))[2]; B1[3]=((const float4*)(Bp+o))[3];
    C1[0]=((const float4*)(Cp+o))[0]; C1[1]=((const float4*)(Cp+o))[1];
    C1[2]=((const float4*)(Cp+o))[2]; C1[3]=((const float4*)(Cp+o))[3];
  }
  for (int tt = 0; tt < SCHUNK; tt += 2){
    {
      int t = t0 + tt;
      float coef = dt0 * x0;
      float accp[4] = {0.f,0.f,0.f,0.f};
      const float* bf = (const float*)B0;
      const float* cf = (const float*)C0;
#pragma unroll
      for (int i = 0; i < 16; i++){
        s[i] = fmaf(s[i], dA0, coef*bf[i]);
        accp[i & 3] = fmaf(s[i], cf[i], accp[i & 3]);
      }
      float accv = (accp[0]+accp[1])+(accp[2]+accp[3]);
      accv += __shfl_xor(accv, 1); accv += __shfl_xor(accv, 2);
      accv += __shfl_xor(accv, 4); accv += __shfl_xor(accv, 8);
      if (nc == 0) ys[(size_t)t*MINTN + h*HEADD + d] = accv + Dh*x0;
      int tn = t0 + ((tt+2 < SCHUNK) ? tt+2 : SCHUNK-1);
      size_t o = (size_t)tn*CONVD;
      x0 = xp[o]; dt0 = dtb[tn*NHEAD + h]; dA0 = dAb[tn*NHEAD + h];
      B0[0]=((const float4*)(Bp+o))[0]; B0[1]=((const float4*)(Bp+o))[1];
      B0[2]=((const float4*)(Bp+o))[2]; B0[3]=((const float4*)(Bp+o))[3];
      C0[0]=((const float4*)(Cp+o))[0]; C0[1]=((const float4*)(Cp+o))[1];
      C0[2]=((const float4*)(Cp+o))[2]; C0[3]=((const float4*)(Cp+o))[3];
    }
    {
      int t = t0 + tt + 1;
      float coef = dt1 * x1;
      float accp[4] = {0.f,0.f,0.f,0.f};
      const float* bf = (const float*)B1;
      const float* cf = (const float*)C1;
#pragma unroll
      for (int i = 0; i < 16; i++){
        s[i] = fmaf(s[i], dA1, coef*bf[i]);
        accp[i & 3] = fmaf(s[i], cf[i], accp[i & 3]);
      }
      float accv = (accp[0]+accp[1])+(accp[2]+accp[3]);
      accv += __shfl_xor(accv, 1); accv += __shfl_xor(accv, 2);
      accv += __shfl_xor(accv, 4); accv += __shfl_xor(accv, 8);
      if (nc == 0) ys[(size_t)t*MINTN + h*HEADD + d] = accv + Dh*x1;
      int tn = t0 + ((tt+3 < SCHUNK) ? tt+3 : SCHUNK-1);
      size_t o = (size_t)tn*CONVD;
      x1 = xp[o]; dt1 = dtb[tn*NHEAD + h]; dA1 = dAb[tn*NHEAD + h];
      B1[0]=((const float4*)(Bp+o))[0]; B1[1]=((const float4*)(Bp+o))[1];
      B1[2]=((const float4*)(Bp+o))[2]; B1[3]=((const float4*)(Bp+o))[3];
      C1[0]=((const float4*)(Cp+o))[0]; C1[1]=((const float4*)(Cp+o))[1];
      C1[2]=((const float4*)(Cp+o))[2]; C1[3]=((const float4*)(Cp+o))[3];
    }
  }
}

// ---------------- small assembly kernels ----------------
__global__ __launch_bounds__(256) void build_hc_k(const float* __restrict__ hn, const float* __restrict__ memo,
                                                  float* __restrict__ hc){
  int idx = blockIdx.x*256 + threadIdx.x;
  if (idx >= TCN*HDIM) return;
  int r = idx >> 10, c = idx & 1023;
  float v;
  if (r < SINKN)        v = hn[(size_t)r*HDIM + c];
  else if (r == SINKN)  v = memo[(size_t)(LMN-1)*HDIM + c];
  else                  v = hn[(size_t)(r + 1663)*HDIM + c];
  hc[idx] = v;
}

__global__ __launch_bounds__(256) void rope_k(float* __restrict__ q, float* __restrict__ k,
                                              const float* __restrict__ cosp, const float* __restrict__ sinp){
  int idx = blockIdx.x*256 + threadIdx.x;
  if (idx >= TCN*20*32) return;
  int dd = idx & 31;
  int hh = (idx >> 5) % 20;
  int t  = idx / (20*32);
  int ci = (t <= SINKN) ? t : t + 1663;
  float* p = (hh < NHEAD) ? (q + (size_t)t*HDIM + hh*HEADD)
                          : (k + (size_t)t*(NKVH*HEADD) + (hh - NHEAD)*HEADD);
  float a = p[dd], b = p[dd+32];
  float c0 = cosp[(size_t)ci*HEADD + dd], c1 = cosp[(size_t)ci*HEADD + dd + 32];
  float s0 = sinp[(size_t)ci*HEADD + dd], s1 = sinp[(size_t)ci*HEADD + dd + 32];
  p[dd]    = a*c0 - b*s0;
  p[dd+32] = b*c1 + a*s1;
}

// ---------------- flash-style fp32 attention ----------------
__global__ __launch_bounds__(256) void attn_k(const float* __restrict__ q, const float* __restrict__ k,
                                              const float* __restrict__ v, float* __restrict__ aoc){
  __shared__ float Qs[64][65];
  __shared__ float Ks[64][65];
  __shared__ float Vs[64][68];
  int qt = blockIdx.x, h = blockIdx.y;
  int tid = threadIdx.x;
  int ql = tid >> 2, dg = tid & 3;
  int qg = qt*64 + ql;
  int kvh = h >> 2;
#pragma unroll
  for (int i = 0; i < 16; i++){
    int idx = tid + 256*i;
    int r = idx >> 6, c = idx & 63;
    int qr = qt*64 + r;
    Qs[r][c] = (qr < TCN) ? q[(size_t)qr*HDIM + h*HEADD + c] : 0.f;
  }
  __syncthreads();
  float qreg[64];
#pragma unroll
  for (int d2 = 0; d2 < 64; d2++) qreg[d2] = Qs[ql][d2];
  __syncthreads();

  float mrun = -INFINITY, lrun = 0.f;
  float acc[16];
#pragma unroll
  for (int i = 0; i < 16; i++) acc[i] = 0.f;

  for (int kt = 0; kt <= qt; kt++){
    __syncthreads();
#pragma unroll
    for (int i = 0; i < 16; i++){
      int idx = tid + 256*i;
      int r = idx >> 6, c = idx & 63;
      int kr = kt*64 + r;
      float kv = 0.f, vv = 0.f;
      if (kr < TCN){
        kv = k[(size_t)kr*(NKVH*HEADD) + kvh*HEADD + c];
        vv = v[(size_t)kr*(NKVH*HEADD) + kvh*HEADD + c];
      }
      Ks[r][c] = kv; Vs[r][c] = vv;
    }
    __syncthreads();
    float p[16]; float tmax = -INFINITY;
#pragma unroll
    for (int jj = 0; jj < 16; jj++){
      int j = jj*4 + dg;
      float sv = 0.f;
#pragma unroll
      for (int d2 = 0; d2 < 64; d2++) sv = fmaf(qreg[d2], Ks[j][d2], sv);
      sv *= 0.125f;
      int kr = kt*64 + j;
      if (kr > qg || kr >= TCN) sv = -INFINITY;
      p[jj] = sv;
      tmax = fmaxf(tmax, sv);
    }
    tmax = fmaxf(tmax, __shfl_xor(tmax, 1));
    tmax = fmaxf(tmax, __shfl_xor(tmax, 2));
    float nm = fmaxf(mrun, tmax);
    if (nm == -INFINITY) nm = 0.f;
    float sc = expf(mrun - nm);
    float sump = 0.f;
#pragma unroll
    for (int jj = 0; jj < 16; jj++){ p[jj] = expf(p[jj] - nm); sump += p[jj]; }
    sump += __shfl_xor(sump, 1);
    sump += __shfl_xor(sump, 2);
    lrun = lrun*sc + sump;
    mrun = nm;
#pragma unroll
    for (int i = 0; i < 16; i++) acc[i] *= sc;
#pragma unroll
    for (int jj = 0; jj < 16; jj++) Qs[ql][jj*4 + dg] = p[jj];
    __syncthreads();
#pragma unroll
    for (int j = 0; j < 64; j++){
      float pv = Qs[ql][j];
#pragma unroll
      for (int c4 = 0; c4 < 4; c4++){
        float4 vv = *(const float4*)&Vs[j][dg*16 + c4*4];
        acc[c4*4+0] = fmaf(pv, vv.x, acc[c4*4+0]);
        acc[c4*4+1] = fmaf(pv, vv.y, acc[c4*4+1]);
        acc[c4*4+2] = fmaf(pv, vv.z, acc[c4*4+2]);
        acc[c4*4+3] = fmaf(pv, vv.w, acc[c4*4+3]);
      }
    }
  }
  if (qg < TCN){
    float inv = 1.0f / lrun;
#pragma unroll
    for (int c4 = 0; c4 < 4; c4++){
      *(float4*)(aoc + (size_t)qg*HDIM + h*HEADD + dg*16 + c4*4) =
          make_float4(acc[c4*4]*inv, acc[c4*4+1]*inv, acc[c4*4+2]*inv, acc[c4*4+3]*inv);
    }
  }
}

__global__ __launch_bounds__(256) void build_ao_k(const float* __restrict__ aoc, const float* __restrict__ memo,
                                                  float* __restrict__ aof){
  int idx = blockIdx.x*256 + threadIdx.x;
  if (idx >= TLEN*HDIM) return;
  int r = idx >> 10, c = idx & 1023;
  float v;
  if (r < SINKN)              v = aoc[(size_t)r*HDIM + c];
  else if (r < TLEN - WINN)   v = memo[(size_t)(r - SINKN)*HDIM + c];
  else                        v = aoc[(size_t)(r - 1663)*HDIM + c];
  aof[idx] = v;
}

extern "C" void kernel_launch(void* const* d_in, const int* in_sizes, int n_in,
                              void* d_out, int out_size, void* d_ws, size_t ws_size,
                              hipStream_t stream){
  (void)in_sizes; (void)n_in; (void)out_size; (void)ws_size;
  const float* x      = (const float*)d_in[0];
  const float* cosp   = (const float*)d_in[1];
  const float* sinp   = (const float*)d_in[2];
  const float* ln1_w  = (const float*)d_in[3];
  const float* q_w    = (const float*)d_in[4];
  const float* q_b    = (const float*)d_in[5];
  const float* k_w    = (const float*)d_in[6];
  const float* k_b    = (const float*)d_in[7];
  const float* v_w    = (const float*)d_in[8];
  const float* v_b    = (const float*)d_in[9];
  const float* o_w    = (const float*)d_in[10];
  const float* inpw   = (const float*)d_in[11];
  const float* convw  = (const float*)d_in[12];
  const float* convb  = (const float*)d_in[13];
  const float* dtbias = (const float*)d_in[14];
  const float* alog   = (const float*)d_in[15];
  const float* Dp     = (const float*)d_in[16];
  const float* mnw    = (const float*)d_in[17];
  const float* moutw  = (const float*)d_in[18];
  const float* ln2_w  = (const float*)d_in[19];
  const float* gatew  = (const float*)d_in[20];
  const float* upw    = (const float*)d_in[21];
  const float* downw  = (const float*)d_in[22];
  float* out = (float*)d_out;

  // Workspace overlay (floats). Peak = 19,216,592 floats = 73.3 MiB (unchanged from R8).
  float* w     = (float*)d_ws;
  float* hn    = w + 0;
  float* proj  = w + 2097152;
  float* conv  = w + 8939520;
  float* memo  = w + 8939520;
  float* mamx  = w + 10643456;
  float* dtb   = w + 14051328;
  float* dAb   = w + 14077952;
  float* yscan = w + 14104576;
  float* hc    = w + 14104576;
  float* qb    = w + 14498816;
  float* kb    = w + 14893056;
  float* vb    = w + 14991616;
  float* aoc   = w + 15090176;
  float* hloc  = w + 15808512;
  float* aQ    = w + 19216384;
  float* aof   = w + 2097152;
  float* h1    = w + 0;
  float* mlpin = w + 2097152;
  float* gbuf  = w + 4194304;   // 2048x4096, gate then silu(gate)*up in-place

  // 1. ln1
  rmsnorm_k<<<TLEN, 256, 0, stream>>>(x, ln1_w, hn);
  // 2. mamba in_proj (MFMA split-bf16): 1664x4112x1024
  mfma_gemm_k<0><<<dim3(33, 13), 256, 0, stream>>>(hn + (size_t)SINKN*HDIM, inpw, proj, nullptr, LMN, DPROJ, HDIM);
  // 3. conv + silu
  conv_silu_k<<<(LMN*CONVD + 255)/256, 256, 0, stream>>>(proj, convw, convb, conv);
  // 4. dt/dA prep
  dtprep_k<<<(LMN*NHEAD + 255)/256, 256, 0, stream>>>(proj, dtbias, alog, dtb, dAb);
  // 5. chunked scan
  chunk_prod_k<<<NCHUNK*NHEAD, 64, 0, stream>>>(dAb, aQ);
  scan_local_k<<<NCHUNK*64, 256, 0, stream>>>(conv, dtb, dAb, hloc);
  chunk_combine_k<<<1024, 256, 0, stream>>>(hloc, aQ);
  scan_out_k<<<NCHUNK*64, 256, 0, stream>>>(conv, dtb, dAb, Dp, hloc, yscan);
  // 6. gate by silu(z), rmsnorm
  gated_rmsnorm_k<<<LMN, 256, 0, stream>>>(yscan, proj, mnw, mamx);
  // 7. mamba out proj (MFMA): 1664x1024x1024
  mfma_gemm_k<0><<<dim3(8, 13), 256, 0, stream>>>(mamx, moutw, memo, nullptr, LMN, HDIM, HDIM);
  // 8. compressed sequence
  build_hc_k<<<(TCN*HDIM + 255)/256, 256, 0, stream>>>(hn, memo, hc);
  // 9-11. qkv (fp32 64-tile; M=385 not 128-multiple, tiny)
  gemm64_k<1><<<dim3(16, 7), 256, 0, stream>>>(hc, q_w, qb, q_b, nullptr, TCN, HDIM, HDIM);
  gemm64_k<1><<<dim3(4, 7), 256, 0, stream>>>(hc, k_w, kb, k_b, nullptr, TCN, NKVH*HEADD, HDIM);
  gemm64_k<1><<<dim3(4, 7), 256, 0, stream>>>(hc, v_w, vb, v_b, nullptr, TCN, NKVH*HEADD, HDIM);
  // 12. rope
  rope_k<<<(TCN*20*32 + 255)/256, 256, 0, stream>>>(qb, kb, cosp, sinp);
  // 13. attention
  attn_k<<<dim3(7, 16), 256, 0, stream>>>(qb, kb, vb, aoc);
  // 14. splice
  build_ao_k<<<(TLEN*HDIM + 255)/256, 256, 0, stream>>>(aoc, memo, aof);
  // 15. o_proj + residual (MFMA): 2048x1024x1024
  mfma_gemm_k<2><<<dim3(8, 16), 256, 0, stream>>>(aof, o_w, h1, x, TLEN, HDIM, HDIM);
  // 16. ln2
  rmsnorm_k<<<TLEN, 256, 0, stream>>>(h1, ln2_w, mlpin);
  // 17. gate proj (MFMA): 2048x4096x1024 -> gbuf
  mfma_gemm_k<0><<<dim3(32, 16), 256, 0, stream>>>(mlpin, gatew, gbuf, nullptr, TLEN, INTERN, HDIM);
  // 18. up proj (MFMA), epilogue gu = silu(gate)*up in-place over gbuf
  mfma_gemm_k<3><<<dim3(32, 16), 256, 0, stream>>>(mlpin, upw, gbuf, gbuf, TLEN, INTERN, HDIM);
  // 19. down proj + residual (MFMA): 2048x1024x4096
  mfma_gemm_k<2><<<dim3(8, 16), 256, 0, stream>>>(gbuf, downw, out, h1, TLEN, HDIM, INTERN);
}